// Round 1
// baseline (742.079 us; speedup 1.0000x reference)
//
#include <hip/hip_runtime.h>
#include <hip/hip_bf16.h>

#define SEQL 2048
#define DIMN 2048
#define NH 16
#define NKV 8
#define HD 128
#define NB 2

typedef float f32v4 __attribute__((ext_vector_type(4)));
typedef __bf16 bfv8 __attribute__((ext_vector_type(8)));
typedef short s16v8 __attribute__((ext_vector_type(8)));
typedef unsigned short u16v4 __attribute__((ext_vector_type(4)));

__device__ inline unsigned short f2bf(float f){
  union { float f; unsigned u; } v; v.f = f;
  unsigned r = (v.u + 0x7fffu + ((v.u >> 16) & 1u)) >> 16;
  return (unsigned short)r;
}
__device__ inline float bf2f(unsigned short u){
  union { unsigned u; float f; } v; v.u = ((unsigned)u) << 16;
  return v.f;
}
__device__ inline f32v4 mfma16(bfv8 a, bfv8 b, f32v4 c){
  return __builtin_amdgcn_mfma_f32_16x16x32_bf16(a, b, c, 0, 0, 0);
}
__device__ inline bfv8 ld8(const unsigned short* p){
  s16v8 v = *reinterpret_cast<const s16v8*>(p);
  return __builtin_bit_cast(bfv8, v);
}

// ---- fp32 -> bf16 convert (vectorized) ----
__global__ __launch_bounds__(256) void cvtk(const float* __restrict__ in,
                                            unsigned short* __restrict__ out, int n4){
  int i = blockIdx.x * 256 + threadIdx.x;
  if (i >= n4) return;
  const float4 v = reinterpret_cast<const float4*>(in)[i];
  u16v4 w; w[0] = f2bf(v.x); w[1] = f2bf(v.y); w[2] = f2bf(v.z); w[3] = f2bf(v.w);
  reinterpret_cast<u16v4*>(out)[i] = w;
}

// ---- C[M,N] = A[M,K] * B[N,K]^T, bf16 in, bf16 or f32 out ----
template<bool CF32>
__global__ __launch_bounds__(256) void gemm_bt(const unsigned short* __restrict__ A,
                                               const unsigned short* __restrict__ B,
                                               void* __restrict__ Cp,
                                               int M, int N, int K){
  __shared__ unsigned short As[128][72];
  __shared__ unsigned short Bs[128][72];
  const int tid = threadIdx.x;
  const int lane = tid & 63;
  const int wave = tid >> 6;
  const int wr = (wave >> 1) * 64, wc = (wave & 1) * 64;
  const int bm = blockIdx.y * 128, bn = blockIdx.x * 128;
  const int l15 = lane & 15, lg = lane >> 4;
  const int srow = tid >> 3;        // 0..31
  const int scol = (tid & 7) * 8;   // 0..56

  f32v4 acc[4][4] = {};
  for (int kt = 0; kt < K; kt += 64){
    #pragma unroll
    for (int p = 0; p < 4; ++p){
      int row = srow + p * 32;
      *reinterpret_cast<s16v8*>(&As[row][scol]) =
        *reinterpret_cast<const s16v8*>(&A[(size_t)(bm + row) * K + kt + scol]);
      *reinterpret_cast<s16v8*>(&Bs[row][scol]) =
        *reinterpret_cast<const s16v8*>(&B[(size_t)(bn + row) * K + kt + scol]);
    }
    __syncthreads();
    #pragma unroll
    for (int kk = 0; kk < 64; kk += 32){
      bfv8 af[4], bfr[4];
      #pragma unroll
      for (int i = 0; i < 4; ++i) af[i] = ld8(&As[wr + i * 16 + l15][kk + lg * 8]);
      #pragma unroll
      for (int j = 0; j < 4; ++j) bfr[j] = ld8(&Bs[wc + j * 16 + l15][kk + lg * 8]);
      #pragma unroll
      for (int i = 0; i < 4; ++i)
        #pragma unroll
        for (int j = 0; j < 4; ++j)
          acc[i][j] = mfma16(af[i], bfr[j], acc[i][j]);
    }
    __syncthreads();
  }
  #pragma unroll
  for (int i = 0; i < 4; ++i){
    #pragma unroll
    for (int j = 0; j < 4; ++j){
      const int gr = bm + wr + i * 16 + lg * 4;
      const int gc = bn + wc + j * 16 + l15;
      #pragma unroll
      for (int r = 0; r < 4; ++r){
        if (CF32) reinterpret_cast<float*>(Cp)[(size_t)(gr + r) * N + gc] = acc[i][j][r];
        else reinterpret_cast<unsigned short*>(Cp)[(size_t)(gr + r) * N + gc] = f2bf(acc[i][j][r]);
      }
    }
  }
}

// ---- RoPE in-place on bf16 [4096][ncols] ----
__global__ __launch_bounds__(256) void ropek(unsigned short* __restrict__ T,
                                             const float* __restrict__ fc,
                                             const float* __restrict__ fs, int ncols){
  int p = blockIdx.x * 256 + threadIdx.x;
  int half = ncols >> 1;
  int row = p / half;
  int pc = p - row * half;
  int h = pc >> 6, i = pc & 63;
  int s = row & (SEQL - 1);
  size_t idx = (size_t)row * ncols + h * HD + 2 * i;
  float r = bf2f(T[idx]), im = bf2f(T[idx + 1]);
  float c = fc[s * 64 + i], sn = fs[s * 64 + i];
  T[idx]     = f2bf(r * c - im * sn);
  T[idx + 1] = f2bf(r * sn + im * c);
}

// ---- V transpose: V[b*SEQ+s][kvh*HD+d] -> Vt[(b*NKV+kvh)*HD+d][s] ----
__global__ __launch_bounds__(256) void vtrans(const unsigned short* __restrict__ V,
                                              unsigned short* __restrict__ Vt){
  __shared__ unsigned short Ts[64][132];
  const int bk = blockIdx.y;        // b*NKV + kvh
  const int st = blockIdx.x * 64;   // s tile base
  const int t = threadIdx.x;
  const int vc = (t & 31) * 4, r0 = t >> 5;
  #pragma unroll
  for (int p = 0; p < 8; ++p){
    int s = r0 + p * 8;
    u16v4 v = *reinterpret_cast<const u16v4*>(
      &V[(size_t)((bk >> 3) * SEQL + st + s) * (NKV * HD) + (bk & 7) * HD + vc]);
    Ts[s][vc] = v[0]; Ts[s][vc + 1] = v[1]; Ts[s][vc + 2] = v[2]; Ts[s][vc + 3] = v[3];
  }
  __syncthreads();
  const int sv = (t & 15) * 4, d0 = t >> 4;
  #pragma unroll
  for (int p = 0; p < 8; ++p){
    int d = d0 + p * 16;
    u16v4 wv_;
    wv_[0] = Ts[sv][d]; wv_[1] = Ts[sv + 1][d]; wv_[2] = Ts[sv + 2][d]; wv_[3] = Ts[sv + 3][d];
    *reinterpret_cast<u16v4*>(&Vt[((size_t)bk * HD + d) * SEQL + st + sv]) = wv_;
  }
}

// ---- flash attention, causal, GQA(2), 4 waves x 16 q-rows, KVB=32 ----
__global__ __launch_bounds__(256) void fattn(const unsigned short* __restrict__ Q,
                                             const unsigned short* __restrict__ K,
                                             const unsigned short* __restrict__ Vt,
                                             unsigned short* __restrict__ O){
  __shared__ unsigned short Pl[4][16][40];
  const int qblk = blockIdx.x, bh = blockIdx.y;
  const int b = bh >> 4, h = bh & 15, kvh = h >> 1;
  const int w = threadIdx.x >> 6, lane = threadIdx.x & 63;
  const int l15 = lane & 15, lg = lane >> 4;
  const int q0 = qblk * 64 + w * 16;

  bfv8 qf[4];
  {
    const unsigned short* qp = Q + (size_t)(b * SEQL + q0 + l15) * DIMN + h * HD + lg * 8;
    #pragma unroll
    for (int c = 0; c < 4; ++c) qf[c] = ld8(qp + c * 32);
  }
  f32v4 outv[8] = {};
  float m[4], l[4];
  #pragma unroll
  for (int r = 0; r < 4; ++r){ m[r] = -1e30f; l[r] = 0.f; }

  const unsigned short* kb = K + (size_t)(b * SEQL) * (NKV * HD) + kvh * HD;
  const unsigned short* vbp = Vt + (size_t)(b * NKV + kvh) * HD * SEQL;
  const int kvend = qblk * 64 + 64;
  const float scale = 0.08838834764831845f;

  for (int kvb = 0; kvb < kvend; kvb += 32){
    f32v4 s0 = {}, s1 = {};
    #pragma unroll
    for (int c = 0; c < 4; ++c){
      const unsigned short* kp = kb + (size_t)(kvb + l15) * (NKV * HD) + c * 32 + lg * 8;
      s0 = mfma16(qf[c], ld8(kp), s0);
      s1 = mfma16(qf[c], ld8(kp + 16 * (NKV * HD)), s1);
    }
    float corr[4];
    #pragma unroll
    for (int r = 0; r < 4; ++r){
      float a = s0[r] * scale, bbv = s1[r] * scale;
      int q = q0 + lg * 4 + r;
      if (kvb + l15 > q) a = -1e30f;
      if (kvb + 16 + l15 > q) bbv = -1e30f;
      float mx = fmaxf(a, bbv);
      mx = fmaxf(mx, __shfl_xor(mx, 1));
      mx = fmaxf(mx, __shfl_xor(mx, 2));
      mx = fmaxf(mx, __shfl_xor(mx, 4));
      mx = fmaxf(mx, __shfl_xor(mx, 8));
      float mn = fmaxf(m[r], mx);
      float cr = __expf(m[r] - mn);
      float e0 = __expf(a - mn), e1 = __expf(bbv - mn);
      float sm = e0 + e1;
      sm += __shfl_xor(sm, 1); sm += __shfl_xor(sm, 2);
      sm += __shfl_xor(sm, 4); sm += __shfl_xor(sm, 8);
      l[r] = l[r] * cr + sm;
      m[r] = mn; corr[r] = cr;
      Pl[w][lg * 4 + r][l15] = f2bf(e0);
      Pl[w][lg * 4 + r][16 + l15] = f2bf(e1);
    }
    #pragma unroll
    for (int dt = 0; dt < 8; ++dt)
      #pragma unroll
      for (int r = 0; r < 4; ++r) outv[dt][r] *= corr[r];
    asm volatile("s_waitcnt lgkmcnt(0)" ::: "memory");
    bfv8 pa = ld8(&Pl[w][l15][lg * 8]);
    #pragma unroll
    for (int dt = 0; dt < 8; ++dt){
      bfv8 vf = ld8(vbp + (size_t)(dt * 16 + l15) * SEQL + kvb + lg * 8);
      outv[dt] = mfma16(pa, vf, outv[dt]);
    }
  }
  float inv[4];
  #pragma unroll
  for (int r = 0; r < 4; ++r) inv[r] = 1.f / l[r];
  #pragma unroll
  for (int dt = 0; dt < 8; ++dt){
    #pragma unroll
    for (int r = 0; r < 4; ++r){
      int q = q0 + lg * 4 + r;
      O[(size_t)(b * SEQL + q) * DIMN + h * HD + dt * 16 + l15] = f2bf(outv[dt][r] * inv[r]);
    }
  }
}

extern "C" void kernel_launch(void* const* d_in, const int* in_sizes, int n_in,
                              void* d_out, int out_size, void* d_ws, size_t ws_size,
                              hipStream_t stream){
  const float* x  = (const float*)d_in[0];
  const float* fc = (const float*)d_in[1];
  const float* fs = (const float*)d_in[2];
  const float* wq = (const float*)d_in[3];
  const float* wk = (const float*)d_in[4];
  const float* wv = (const float*)d_in[5];
  const float* wo = (const float*)d_in[6];
  float* out = (float*)d_out;
  char* ws = (char*)d_ws;
  unsigned short* xb  = (unsigned short*)(ws);              // 16 MB
  unsigned short* wqb = (unsigned short*)(ws + 16777216);   // 8 MB
  unsigned short* wkb = (unsigned short*)(ws + 25165824);   // 4 MB
  unsigned short* wvb = (unsigned short*)(ws + 29360128);   // 4 MB
  unsigned short* wob = (unsigned short*)(ws + 33554432);   // 8 MB
  unsigned short* Qb  = (unsigned short*)(ws + 41943040);   // 16 MB
  unsigned short* Kb  = (unsigned short*)(ws + 58720256);   // 8 MB
  unsigned short* Vb  = (unsigned short*)(ws + 67108864);   // 8 MB
  unsigned short* Vtb = (unsigned short*)(ws + 75497472);   // 8 MB
  unsigned short* Ab  = (unsigned short*)(ws + 83886080);   // 16 MB

  dim3 blk(256);
  cvtk<<<dim3(8192), blk, 0, stream>>>(x,  xb,  2097152);
  cvtk<<<dim3(4096), blk, 0, stream>>>(wq, wqb, 1048576);
  cvtk<<<dim3(2048), blk, 0, stream>>>(wk, wkb, 524288);
  cvtk<<<dim3(2048), blk, 0, stream>>>(wv, wvb, 524288);
  cvtk<<<dim3(4096), blk, 0, stream>>>(wo, wob, 1048576);
  gemm_bt<false><<<dim3(16, 32), blk, 0, stream>>>(xb, wqb, Qb, 4096, 2048, 2048);
  gemm_bt<false><<<dim3(8, 32),  blk, 0, stream>>>(xb, wkb, Kb, 4096, 1024, 2048);
  gemm_bt<false><<<dim3(8, 32),  blk, 0, stream>>>(xb, wvb, Vb, 4096, 1024, 2048);
  ropek<<<dim3(16384), blk, 0, stream>>>(Qb, fc, fs, 2048);
  ropek<<<dim3(8192),  blk, 0, stream>>>(Kb, fc, fs, 1024);
  vtrans<<<dim3(32, 16), blk, 0, stream>>>(Vb, Vtb);
  fattn<<<dim3(32, 32), blk, 0, stream>>>(Qb, Kb, Vtb, Ab);
  gemm_bt<true><<<dim3(16, 32), blk, 0, stream>>>(Ab, wob, out, 4096, 2048, 2048);
}

// Round 2
// 444.151 us; speedup vs baseline: 1.6708x; 1.6708x over previous
//
#include <hip/hip_runtime.h>
#include <hip/hip_bf16.h>

#define SEQL 2048
#define DIMN 2048
#define NH 16
#define NKV 8
#define HD 128
#define NB 2

typedef float f32v4 __attribute__((ext_vector_type(4)));
typedef float f32v16 __attribute__((ext_vector_type(16)));
typedef __bf16 bfv8 __attribute__((ext_vector_type(8)));
typedef short s16v8 __attribute__((ext_vector_type(8)));
typedef unsigned short u16v4 __attribute__((ext_vector_type(4)));
typedef unsigned int u32v4 __attribute__((ext_vector_type(4)));

__device__ inline unsigned short f2bf(float f){
  union { float f; unsigned u; } v; v.f = f;
  unsigned r = (v.u + 0x7fffu + ((v.u >> 16) & 1u)) >> 16;
  return (unsigned short)r;
}
__device__ inline float bf2f(unsigned short u){
  union { unsigned u; float f; } v; v.u = ((unsigned)u) << 16;
  return v.f;
}
__device__ inline f32v4 mfma16(bfv8 a, bfv8 b, f32v4 c){
  return __builtin_amdgcn_mfma_f32_16x16x32_bf16(a, b, c, 0, 0, 0);
}
__device__ inline f32v16 mfma32(bfv8 a, bfv8 b, f32v16 c){
  return __builtin_amdgcn_mfma_f32_32x32x16_bf16(a, b, c, 0, 0, 0);
}
__device__ inline bfv8 ld8(const unsigned short* p){
  s16v8 v = *reinterpret_cast<const s16v8*>(p);
  return __builtin_bit_cast(bfv8, v);
}

// ---- fp32 -> bf16 convert (vectorized) ----
__global__ __launch_bounds__(256) void cvtk(const float* __restrict__ in,
                                            unsigned short* __restrict__ out, int n4){
  int i = blockIdx.x * 256 + threadIdx.x;
  if (i >= n4) return;
  const float4 v = reinterpret_cast<const float4*>(in)[i];
  u16v4 w; w[0] = f2bf(v.x); w[1] = f2bf(v.y); w[2] = f2bf(v.z); w[3] = f2bf(v.w);
  reinterpret_cast<u16v4*>(out)[i] = w;
}

// ---- C[M,N] = A[M,K] * B[N,K]^T, bf16 in, bf16 or f32 out ----
template<bool CF32>
__global__ __launch_bounds__(256) void gemm_bt(const unsigned short* __restrict__ A,
                                               const unsigned short* __restrict__ B,
                                               void* __restrict__ Cp,
                                               int M, int N, int K){
  __shared__ unsigned short As[128][72];
  __shared__ unsigned short Bs[128][72];
  const int tid = threadIdx.x;
  const int lane = tid & 63;
  const int wave = tid >> 6;
  const int wr = (wave >> 1) * 64, wc = (wave & 1) * 64;
  const int bm = blockIdx.y * 128, bn = blockIdx.x * 128;
  const int l15 = lane & 15, lg = lane >> 4;
  const int srow = tid >> 3;        // 0..31
  const int scol = (tid & 7) * 8;   // 0..56

  f32v4 acc[4][4] = {};
  for (int kt = 0; kt < K; kt += 64){
    #pragma unroll
    for (int p = 0; p < 4; ++p){
      int row = srow + p * 32;
      *reinterpret_cast<s16v8*>(&As[row][scol]) =
        *reinterpret_cast<const s16v8*>(&A[(size_t)(bm + row) * K + kt + scol]);
      *reinterpret_cast<s16v8*>(&Bs[row][scol]) =
        *reinterpret_cast<const s16v8*>(&B[(size_t)(bn + row) * K + kt + scol]);
    }
    __syncthreads();
    #pragma unroll
    for (int kk = 0; kk < 64; kk += 32){
      bfv8 af[4], bfr[4];
      #pragma unroll
      for (int i = 0; i < 4; ++i) af[i] = ld8(&As[wr + i * 16 + l15][kk + lg * 8]);
      #pragma unroll
      for (int j = 0; j < 4; ++j) bfr[j] = ld8(&Bs[wc + j * 16 + l15][kk + lg * 8]);
      #pragma unroll
      for (int i = 0; i < 4; ++i)
        #pragma unroll
        for (int j = 0; j < 4; ++j)
          acc[i][j] = mfma16(af[i], bfr[j], acc[i][j]);
    }
    __syncthreads();
  }
  #pragma unroll
  for (int i = 0; i < 4; ++i){
    #pragma unroll
    for (int j = 0; j < 4; ++j){
      const int gr = bm + wr + i * 16 + lg * 4;
      const int gc = bn + wc + j * 16 + l15;
      #pragma unroll
      for (int r = 0; r < 4; ++r){
        if (CF32) reinterpret_cast<float*>(Cp)[(size_t)(gr + r) * N + gc] = acc[i][j][r];
        else reinterpret_cast<unsigned short*>(Cp)[(size_t)(gr + r) * N + gc] = f2bf(acc[i][j][r]);
      }
    }
  }
}

// ---- RoPE in-place on bf16 [4096][ncols] ----
__global__ __launch_bounds__(256) void ropek(unsigned short* __restrict__ T,
                                             const float* __restrict__ fc,
                                             const float* __restrict__ fs, int ncols){
  int p = blockIdx.x * 256 + threadIdx.x;
  int half = ncols >> 1;
  int row = p / half;
  int pc = p - row * half;
  int h = pc >> 6, i = pc & 63;
  int s = row & (SEQL - 1);
  size_t idx = (size_t)row * ncols + h * HD + 2 * i;
  float r = bf2f(T[idx]), im = bf2f(T[idx + 1]);
  float c = fc[s * 64 + i], sn = fs[s * 64 + i];
  T[idx]     = f2bf(r * c - im * sn);
  T[idx + 1] = f2bf(r * sn + im * c);
}

// ---- V transpose: V[b*SEQ+s][kvh*HD+d] -> Vt[(b*NKV+kvh)*HD+d][s] ----
__global__ __launch_bounds__(256) void vtrans(const unsigned short* __restrict__ V,
                                              unsigned short* __restrict__ Vt){
  __shared__ unsigned short Ts[64][132];
  const int bk = blockIdx.y;        // b*NKV + kvh
  const int st = blockIdx.x * 64;   // s tile base
  const int t = threadIdx.x;
  const int vc = (t & 31) * 4, r0 = t >> 5;
  #pragma unroll
  for (int p = 0; p < 8; ++p){
    int s = r0 + p * 8;
    u16v4 v = *reinterpret_cast<const u16v4*>(
      &V[(size_t)((bk >> 3) * SEQL + st + s) * (NKV * HD) + (bk & 7) * HD + vc]);
    Ts[s][vc] = v[0]; Ts[s][vc + 1] = v[1]; Ts[s][vc + 2] = v[2]; Ts[s][vc + 3] = v[3];
  }
  __syncthreads();
  const int sv = (t & 15) * 4, d0 = t >> 4;
  #pragma unroll
  for (int p = 0; p < 8; ++p){
    int d = d0 + p * 16;
    u16v4 wv_;
    wv_[0] = Ts[sv][d]; wv_[1] = Ts[sv + 1][d]; wv_[2] = Ts[sv + 2][d]; wv_[3] = Ts[sv + 3][d];
    *reinterpret_cast<u16v4*>(&Vt[((size_t)bk * HD + d) * SEQL + st + sv]) = wv_;
  }
}

// ---- flash attention, causal, GQA(2): swapped-operand 32x32 MFMA ----
// 2 waves/block, each wave owns 32 q rows. Lane c=lane&31 owns q-column q0+c.
// QK^T computed as mfma(Kfrag, Q^Tfrag) -> S^T: lane holds S[kv_r][q=c],
// kv_r = (r&3)+8*(r>>2)+4*hi. Softmax per-lane in registers (1 shfl_xor(32)).
// PV as mfma(Vtfrag, P^Tfrag) -> O^T accumulator; rescale is per-lane scalar.
__global__ __launch_bounds__(128) void fattn2(const unsigned short* __restrict__ Q,
                                              const unsigned short* __restrict__ K,
                                              const unsigned short* __restrict__ Vt,
                                              unsigned short* __restrict__ O){
  __shared__ __align__(16) unsigned short Ts[2][32][40];
  const int qblk = 31 - blockIdx.x;          // heavy causal blocks dispatch first
  const int bh = blockIdx.y;
  const int b = bh >> 4, h = bh & 15, kvh = h >> 1;
  const int w = threadIdx.x >> 6, lane = threadIdx.x & 63;
  const int c = lane & 31, hi = lane >> 5;
  const int q0 = qblk * 64 + w * 32;
  const int q = q0 + c;

  // Q^T B-fragments: lane holds Q[q0+c][ds*16 + hi*8 + j]
  bfv8 qf[8];
  {
    const unsigned short* qp = Q + (size_t)(b * SEQL + q) * DIMN + h * HD + hi * 8;
    #pragma unroll
    for (int ds = 0; ds < 8; ++ds) qf[ds] = ld8(qp + ds * 16);
  }

  f32v16 o0 = {}, o1 = {}, o2 = {}, o3 = {};
  float m = -1e30f, l = 0.f;
  const float c1 = 0.08838834764831845f * 1.44269504088896f; // scale * log2(e)

  const unsigned short* kbase = K + (size_t)(b * SEQL) * (NKV * HD) + kvh * HD + hi * 8;
  const unsigned short* vbase = Vt + ((size_t)(b * NKV + kvh) * HD + c) * SEQL + hi * 8;

  for (int kvb = 0; kvb < q0 + 32; kvb += 32){
    // S^T = K * Q^T  (A rows = kv, B cols = q)
    f32v16 s = {};
    const unsigned short* kp = kbase + (size_t)(kvb + c) * (NKV * HD);
    #pragma unroll
    for (int ds = 0; ds < 8; ++ds) s = mfma32(ld8(kp + ds * 16), qf[ds], s);

    // scale into log2 domain + causal mask
    float t[16];
    #pragma unroll
    for (int r = 0; r < 16; ++r){
      int kvr = kvb + (r & 3) + 8 * (r >> 2) + 4 * hi;
      t[r] = (kvr <= q) ? s[r] * c1 : -3.0e38f;
    }
    float mx = t[0];
    #pragma unroll
    for (int r = 1; r < 16; ++r) mx = fmaxf(mx, t[r]);
    mx = fmaxf(mx, __shfl_xor(mx, 32));

    // defer-max rescale (T13): only rescale when max grows >8 (log2 units)
    if (!__all(mx - m <= 8.f)){
      float mn = fmaxf(m, mx);
      float corr = __builtin_exp2f(m - mn);
      l *= corr;
      #pragma unroll
      for (int r = 0; r < 16; ++r){ o0[r]*=corr; o1[r]*=corr; o2[r]*=corr; o3[r]*=corr; }
      m = mn;
    }

    float p[16], lsum = 0.f;
    #pragma unroll
    for (int r = 0; r < 16; ++r){ p[r] = __builtin_exp2f(t[r] - m); lsum += p[r]; }
    lsum += __shfl_xor(lsum, 32);
    l += lsum;

    // pack P to bf16 words, one 32-lane swap to build P^T B-fragments
    unsigned w32[8], sw32[8];
    #pragma unroll
    for (int i = 0; i < 8; ++i){
      unsigned short lo = __builtin_bit_cast(unsigned short, (__bf16)p[2*i]);
      unsigned short hb = __builtin_bit_cast(unsigned short, (__bf16)p[2*i+1]);
      w32[i] = (unsigned)lo | ((unsigned)hb << 16);
    }
    #pragma unroll
    for (int i = 0; i < 8; ++i) sw32[i] = (unsigned)__shfl_xor((int)w32[i], 32);
    u32v4 f0u, f1u;
    if (hi){
      f0u[0]=sw32[2]; f0u[1]=sw32[3]; f0u[2]=w32[2];  f0u[3]=w32[3];
      f1u[0]=sw32[6]; f1u[1]=sw32[7]; f1u[2]=w32[6];  f1u[3]=w32[7];
    } else {
      f0u[0]=w32[0];  f0u[1]=w32[1];  f0u[2]=sw32[0]; f0u[3]=sw32[1];
      f1u[0]=w32[4];  f1u[1]=w32[5];  f1u[2]=sw32[4]; f1u[3]=sw32[5];
    }
    bfv8 pf0 = __builtin_bit_cast(bfv8, f0u);
    bfv8 pf1 = __builtin_bit_cast(bfv8, f1u);

    // O^T += V^T * P^T   (A rows = d, B cols = q)
    const unsigned short* vp = vbase + kvb;
    o0 = mfma32(ld8(vp),               pf0, o0);
    o0 = mfma32(ld8(vp + 16),          pf1, o0);
    o1 = mfma32(ld8(vp + 32*SEQL),     pf0, o1);
    o1 = mfma32(ld8(vp + 32*SEQL+16),  pf1, o1);
    o2 = mfma32(ld8(vp + 64*SEQL),     pf0, o2);
    o2 = mfma32(ld8(vp + 64*SEQL+16),  pf1, o2);
    o3 = mfma32(ld8(vp + 96*SEQL),     pf0, o3);
    o3 = mfma32(ld8(vp + 96*SEQL+16),  pf1, o3);
  }

  const float inv = 1.f / l;
  // epilogue: transpose O^T -> O rows via per-wave LDS, 16B coalesced stores
  #define EPI(ODT, DT) \
  { \
    _Pragma("unroll") \
    for (int r = 0; r < 16; ++r) \
      Ts[w][c][(r & 3) + 8 * (r >> 2) + 4 * hi] = f2bf(ODT[r] * inv); \
    asm volatile("s_waitcnt lgkmcnt(0)" ::: "memory"); \
    _Pragma("unroll") \
    for (int pz = 0; pz < 2; ++pz){ \
      int qr = (lane >> 2) + pz * 16; \
      int dcol = (lane & 3) * 8; \
      s16v8 val = *reinterpret_cast<const s16v8*>(&Ts[w][qr][dcol]); \
      *reinterpret_cast<s16v8*>(&O[(size_t)(b * SEQL + q0 + qr) * DIMN + h * HD + DT * 32 + dcol]) = val; \
    } \
    asm volatile("s_waitcnt lgkmcnt(0)" ::: "memory"); \
  }
  EPI(o0, 0) EPI(o1, 1) EPI(o2, 2) EPI(o3, 3)
  #undef EPI
}

extern "C" void kernel_launch(void* const* d_in, const int* in_sizes, int n_in,
                              void* d_out, int out_size, void* d_ws, size_t ws_size,
                              hipStream_t stream){
  const float* x  = (const float*)d_in[0];
  const float* fc = (const float*)d_in[1];
  const float* fs = (const float*)d_in[2];
  const float* wq = (const float*)d_in[3];
  const float* wk = (const float*)d_in[4];
  const float* wv = (const float*)d_in[5];
  const float* wo = (const float*)d_in[6];
  float* out = (float*)d_out;
  char* ws = (char*)d_ws;
  unsigned short* xb  = (unsigned short*)(ws);              // 16 MB
  unsigned short* wqb = (unsigned short*)(ws + 16777216);   // 8 MB
  unsigned short* wkb = (unsigned short*)(ws + 25165824);   // 4 MB
  unsigned short* wvb = (unsigned short*)(ws + 29360128);   // 4 MB
  unsigned short* wob = (unsigned short*)(ws + 33554432);   // 8 MB
  unsigned short* Qb  = (unsigned short*)(ws + 41943040);   // 16 MB
  unsigned short* Kb  = (unsigned short*)(ws + 58720256);   // 8 MB
  unsigned short* Vb  = (unsigned short*)(ws + 67108864);   // 8 MB
  unsigned short* Vtb = (unsigned short*)(ws + 75497472);   // 8 MB
  unsigned short* Ab  = (unsigned short*)(ws + 83886080);   // 16 MB

  dim3 blk(256);
  cvtk<<<dim3(8192), blk, 0, stream>>>(x,  xb,  2097152);
  cvtk<<<dim3(4096), blk, 0, stream>>>(wq, wqb, 1048576);
  cvtk<<<dim3(2048), blk, 0, stream>>>(wk, wkb, 524288);
  cvtk<<<dim3(2048), blk, 0, stream>>>(wv, wvb, 524288);
  cvtk<<<dim3(4096), blk, 0, stream>>>(wo, wob, 1048576);
  gemm_bt<false><<<dim3(16, 32), blk, 0, stream>>>(xb, wqb, Qb, 4096, 2048, 2048);
  gemm_bt<false><<<dim3(8, 32),  blk, 0, stream>>>(xb, wkb, Kb, 4096, 1024, 2048);
  gemm_bt<false><<<dim3(8, 32),  blk, 0, stream>>>(xb, wvb, Vb, 4096, 1024, 2048);
  ropek<<<dim3(16384), blk, 0, stream>>>(Qb, fc, fs, 2048);
  ropek<<<dim3(8192),  blk, 0, stream>>>(Kb, fc, fs, 1024);
  vtrans<<<dim3(32, 16), blk, 0, stream>>>(Vb, Vtb);
  fattn2<<<dim3(32, 32), dim3(128), 0, stream>>>(Qb, Kb, Vtb, Ab);
  gemm_bt<true><<<dim3(16, 32), blk, 0, stream>>>(Ab, wob, out, 4096, 2048, 2048);
}

// Round 3
// 312.792 us; speedup vs baseline: 2.3724x; 1.4200x over previous
//
#include <hip/hip_runtime.h>
#include <hip/hip_bf16.h>

#define SEQL 2048
#define DIMN 2048
#define NH 16
#define NKV 8
#define HD 128
#define NB 2

typedef float f32v4 __attribute__((ext_vector_type(4)));
typedef float f32v16 __attribute__((ext_vector_type(16)));
typedef __bf16 bfv8 __attribute__((ext_vector_type(8)));
typedef short s16v8 __attribute__((ext_vector_type(8)));
typedef unsigned short u16v4 __attribute__((ext_vector_type(4)));
typedef unsigned int u32v4 __attribute__((ext_vector_type(4)));

__device__ inline unsigned short f2bf(float f){
  union { float f; unsigned u; } v; v.f = f;
  unsigned r = (v.u + 0x7fffu + ((v.u >> 16) & 1u)) >> 16;
  return (unsigned short)r;
}
__device__ inline float bf2f(unsigned short u){
  union { unsigned u; float f; } v; v.u = ((unsigned)u) << 16;
  return v.f;
}
__device__ inline f32v4 mfma16(bfv8 a, bfv8 b, f32v4 c){
  return __builtin_amdgcn_mfma_f32_16x16x32_bf16(a, b, c, 0, 0, 0);
}
__device__ inline f32v16 mfma32(bfv8 a, bfv8 b, f32v16 c){
  return __builtin_amdgcn_mfma_f32_32x32x16_bf16(a, b, c, 0, 0, 0);
}
__device__ inline bfv8 ld8(const unsigned short* p){
  s16v8 v = *reinterpret_cast<const s16v8*>(p);
  return __builtin_bit_cast(bfv8, v);
}
__device__ inline void gload16(const void* g, void* l){
  __builtin_amdgcn_global_load_lds(
      (const __attribute__((address_space(1))) unsigned int*)g,
      (__attribute__((address_space(3))) unsigned int*)l, 16, 0, 0);
}

// ---- fp32 -> bf16 convert (vectorized) ----
__global__ __launch_bounds__(256) void cvtk(const float* __restrict__ in,
                                            unsigned short* __restrict__ out, int n4){
  int i = blockIdx.x * 256 + threadIdx.x;
  if (i >= n4) return;
  const float4 v = reinterpret_cast<const float4*>(in)[i];
  u16v4 w; w[0] = f2bf(v.x); w[1] = f2bf(v.y); w[2] = f2bf(v.z); w[3] = f2bf(v.w);
  reinterpret_cast<u16v4*>(out)[i] = w;
}

// ---- C[M,N] = A[M,K] * B[N,K]^T, m97 structure: global_load_lds staging ----
template<bool CF32>
__global__ __launch_bounds__(256) void gemm2(const unsigned short* __restrict__ A,
                                             const unsigned short* __restrict__ B,
                                             void* __restrict__ Cp,
                                             int M, int N, int K){
  __shared__ unsigned short As[128 * 64];
  __shared__ unsigned short Bs[128 * 64];
  const int tid = threadIdx.x;
  const int lane = tid & 63;
  const int wave = tid >> 6;
  const int wr = (wave >> 1) * 64, wc = (wave & 1) * 64;
  const int bm = blockIdx.y * 128, bn = blockIdx.x * 128;
  const int l15 = lane & 15, lg = lane >> 4;
  const int lr = lane >> 3, lc = (lane & 7) * 8;

  f32v4 acc[4][4] = {};
  for (int kt = 0; kt < K; kt += 64){
    #pragma unroll
    for (int p = 0; p < 4; ++p){
      const int row = p * 32 + wave * 8 + lr;
      const int ldso = p * 2048 + wave * 512;
      gload16(&A[(size_t)(bm + row) * K + kt + lc], &As[ldso]);
      gload16(&B[(size_t)(bn + row) * K + kt + lc], &Bs[ldso]);
    }
    __syncthreads();
    #pragma unroll
    for (int kk = 0; kk < 64; kk += 32){
      bfv8 af[4], bfr[4];
      #pragma unroll
      for (int i = 0; i < 4; ++i) af[i] = ld8(&As[(wr + i * 16 + l15) * 64 + kk + lg * 8]);
      #pragma unroll
      for (int j = 0; j < 4; ++j) bfr[j] = ld8(&Bs[(wc + j * 16 + l15) * 64 + kk + lg * 8]);
      #pragma unroll
      for (int i = 0; i < 4; ++i)
        #pragma unroll
        for (int j = 0; j < 4; ++j)
          acc[i][j] = mfma16(af[i], bfr[j], acc[i][j]);
    }
    __syncthreads();
  }
  #pragma unroll
  for (int i = 0; i < 4; ++i){
    #pragma unroll
    for (int j = 0; j < 4; ++j){
      const int gr = bm + wr + i * 16 + lg * 4;
      const int gc = bn + wc + j * 16 + l15;
      #pragma unroll
      for (int r = 0; r < 4; ++r){
        if (CF32) reinterpret_cast<float*>(Cp)[(size_t)(gr + r) * N + gc] = acc[i][j][r];
        else reinterpret_cast<unsigned short*>(Cp)[(size_t)(gr + r) * N + gc] = f2bf(acc[i][j][r]);
      }
    }
  }
}

// ---- RoPE in-place on bf16 [rows][ncols] (Q only) ----
__global__ __launch_bounds__(256) void ropek(unsigned short* __restrict__ T,
                                             const float* __restrict__ fc,
                                             const float* __restrict__ fs, int ncols){
  int p = blockIdx.x * 256 + threadIdx.x;
  int half = ncols >> 1;
  int row = p / half;
  int pc = p - row * half;
  int h = pc >> 6, i = pc & 63;
  int s = row & (SEQL - 1);
  size_t idx = (size_t)row * ncols + h * HD + 2 * i;
  float r = bf2f(T[idx]), im = bf2f(T[idx + 1]);
  float c = fc[s * 64 + i], sn = fs[s * 64 + i];
  T[idx]     = f2bf(r * c - im * sn);
  T[idx + 1] = f2bf(r * sn + im * c);
}

// ---- K swizzle + fused RoPE: Kb raw -> Kf fragment-major ----
// Kf chunk per (bk, kv32): [ds 0..7][lane 0..63][j 0..7],
// value = rope(K)[s = kv32*32 + (l&31)][d = ds*16 + (l>>5)*8 + j]
__global__ __launch_bounds__(256) void kswz(const unsigned short* __restrict__ Kb,
                                            const float* __restrict__ fc,
                                            const float* __restrict__ fs,
                                            unsigned short* __restrict__ Kf){
  __shared__ unsigned short Ks[32][132];
  const int bk = blockIdx.y, kv32 = blockIdx.x;
  const int b = bk >> 3, kvh = bk & 7;
  const int t = threadIdx.x;
  const int r = t >> 3, cc = (t & 7) * 16;
  const int s = kv32 * 32 + r;
  const unsigned short* src = Kb + (size_t)(b * SEQL + s) * (NKV * HD) + kvh * HD + cc;
  s16v8 v0 = *reinterpret_cast<const s16v8*>(src);
  s16v8 v1 = *reinterpret_cast<const s16v8*>(src + 8);
  float4 c0 = *reinterpret_cast<const float4*>(&fc[s * 64 + (cc >> 1)]);
  float4 c1 = *reinterpret_cast<const float4*>(&fc[s * 64 + (cc >> 1) + 4]);
  float4 sv0 = *reinterpret_cast<const float4*>(&fs[s * 64 + (cc >> 1)]);
  float4 sv1 = *reinterpret_cast<const float4*>(&fs[s * 64 + (cc >> 1) + 4]);
  float cA[8] = {c0.x, c0.y, c0.z, c0.w, c1.x, c1.y, c1.z, c1.w};
  float sA[8] = {sv0.x, sv0.y, sv0.z, sv0.w, sv1.x, sv1.y, sv1.z, sv1.w};
  unsigned short e[16];
  #pragma unroll
  for (int k = 0; k < 8; ++k){ e[k] = (unsigned short)v0[k]; e[k + 8] = (unsigned short)v1[k]; }
  #pragma unroll
  for (int pi = 0; pi < 8; ++pi){
    float re = bf2f(e[2 * pi]), im = bf2f(e[2 * pi + 1]);
    Ks[r][cc + 2 * pi]     = f2bf(re * cA[pi] - im * sA[pi]);
    Ks[r][cc + 2 * pi + 1] = f2bf(re * sA[pi] + im * cA[pi]);
  }
  __syncthreads();
  const int l = t & 63;
  #pragma unroll
  for (int p = 0; p < 2; ++p){
    int ds = (t >> 6) * 2 + p;
    s16v8 val = *reinterpret_cast<const s16v8*>(&Ks[l & 31][ds * 16 + (l >> 5) * 8]);
    *reinterpret_cast<s16v8*>(&Kf[(((size_t)bk * 64 + kv32) * 8 + ds) * 512 + (size_t)l * 8]) = val;
  }
}

// ---- V swizzle: Vb raw -> Vf fragment-major ----
// Vf chunk per (bk, kv32): [dt*2+h2][lane][j],
// value = V[s = kv32*32 + h2*16 + (l>>5)*8 + j][d = dt*32 + (l&31)]
__global__ __launch_bounds__(256) void vswz(const unsigned short* __restrict__ Vb,
                                            unsigned short* __restrict__ Vf){
  __shared__ unsigned short Vs[32][132];
  const int bk = blockIdx.y, kv32 = blockIdx.x;
  const int b = bk >> 3, kvh = bk & 7;
  const int t = threadIdx.x;
  const int r = t >> 3, cc = (t & 7) * 16;
  const int s = kv32 * 32 + r;
  const unsigned short* src = Vb + (size_t)(b * SEQL + s) * (NKV * HD) + kvh * HD + cc;
  *reinterpret_cast<s16v8*>(&Vs[r][cc])     = *reinterpret_cast<const s16v8*>(src);
  *reinterpret_cast<s16v8*>(&Vs[r][cc + 8]) = *reinterpret_cast<const s16v8*>(src + 8);
  __syncthreads();
  const int dt = t >> 6, l = t & 63;
  #pragma unroll
  for (int h2 = 0; h2 < 2; ++h2){
    s16v8 val;
    #pragma unroll
    for (int j = 0; j < 8; ++j)
      val[j] = (short)Vs[h2 * 16 + (l >> 5) * 8 + j][dt * 32 + (l & 31)];
    *reinterpret_cast<s16v8*>(&Vf[(((size_t)bk * 64 + kv32) * 8 + dt * 2 + h2) * 512 + (size_t)l * 8]) = val;
  }
}

// ---- flash attention, causal, GQA(2): swapped 32x32, fragment-major K/V ----
__global__ __launch_bounds__(128) void fattn3(const unsigned short* __restrict__ Q,
                                              const unsigned short* __restrict__ Kf,
                                              const unsigned short* __restrict__ Vf,
                                              unsigned short* __restrict__ O){
  __shared__ __align__(16) unsigned short Ts[2][32][40];
  const int id = blockIdx.x;
  // XCD-affine swizzle: same bh group -> same XCD; heavy qblk first
  const int xcd = id & 7, sub = (id >> 3) & 3, qr_ = id >> 5;
  const int bh = xcd * 4 + sub;
  const int qblk = 31 - qr_;
  const int b = bh >> 4, h = bh & 15, kvh = h >> 1;
  const int bk = b * NKV + kvh;
  const int w = threadIdx.x >> 6, lane = threadIdx.x & 63;
  const int c = lane & 31, hi = lane >> 5;
  const int q0 = qblk * 64 + w * 32;
  const int q = q0 + c;

  bfv8 qf[8];
  {
    const unsigned short* qp = Q + (size_t)(b * SEQL + q) * DIMN + h * HD + hi * 8;
    #pragma unroll
    for (int ds = 0; ds < 8; ++ds) qf[ds] = ld8(qp + ds * 16);
  }

  f32v16 o0 = {}, o1 = {}, o2 = {}, o3 = {};
  float m = -1e30f, l = 0.f;
  const float c1 = 0.08838834764831845f * 1.44269504088896f;

  const unsigned short* kfb = Kf + ((size_t)bk * 64) * 4096 + (size_t)lane * 8;
  const unsigned short* vfb = Vf + ((size_t)bk * 64) * 4096 + (size_t)lane * 8;
  const int niter = (q0 >> 5) + 1;

  bfv8 kf[8];
  #pragma unroll
  for (int ds = 0; ds < 8; ++ds) kf[ds] = ld8(kfb + ds * 512);

  for (int it = 0; it < niter; ++it){
    f32v16 s = {};
    #pragma unroll
    for (int ds = 0; ds < 8; ++ds) s = mfma32(kf[ds], qf[ds], s);

    // prefetch next K chunk (hides under softmax)
    if (it + 1 < niter){
      const unsigned short* kn = kfb + (size_t)(it + 1) * 4096;
      #pragma unroll
      for (int ds = 0; ds < 8; ++ds) kf[ds] = ld8(kn + ds * 512);
    }

    const int kvb = it * 32;
    float t[16];
    #pragma unroll
    for (int r = 0; r < 16; ++r){
      int kvr = kvb + (r & 3) + 8 * (r >> 2) + 4 * hi;
      t[r] = (kvr <= q) ? s[r] * c1 : -3.0e38f;
    }
    float mx = t[0];
    #pragma unroll
    for (int r = 1; r < 16; ++r) mx = fmaxf(mx, t[r]);
    mx = fmaxf(mx, __shfl_xor(mx, 32));

    if (!__all(mx - m <= 8.f)){
      float mn = fmaxf(m, mx);
      float corr = __builtin_exp2f(m - mn);
      l *= corr;
      #pragma unroll
      for (int r = 0; r < 16; ++r){ o0[r]*=corr; o1[r]*=corr; o2[r]*=corr; o3[r]*=corr; }
      m = mn;
    }

    float p[16], lsum = 0.f;
    #pragma unroll
    for (int r = 0; r < 16; ++r){ p[r] = __builtin_exp2f(t[r] - m); lsum += p[r]; }
    lsum += __shfl_xor(lsum, 32);
    l += lsum;

    unsigned w32[8], sw32[8];
    #pragma unroll
    for (int i = 0; i < 8; ++i){
      unsigned short lo = __builtin_bit_cast(unsigned short, (__bf16)p[2*i]);
      unsigned short hb = __builtin_bit_cast(unsigned short, (__bf16)p[2*i+1]);
      w32[i] = (unsigned)lo | ((unsigned)hb << 16);
    }
    #pragma unroll
    for (int i = 0; i < 8; ++i) sw32[i] = (unsigned)__shfl_xor((int)w32[i], 32);
    u32v4 f0u, f1u;
    if (hi){
      f0u[0]=sw32[2]; f0u[1]=sw32[3]; f0u[2]=w32[2];  f0u[3]=w32[3];
      f1u[0]=sw32[6]; f1u[1]=sw32[7]; f1u[2]=w32[6];  f1u[3]=w32[7];
    } else {
      f0u[0]=w32[0];  f0u[1]=w32[1];  f0u[2]=sw32[0]; f0u[3]=sw32[1];
      f1u[0]=w32[4];  f1u[1]=w32[5];  f1u[2]=sw32[4]; f1u[3]=sw32[5];
    }
    bfv8 pf0 = __builtin_bit_cast(bfv8, f0u);
    bfv8 pf1 = __builtin_bit_cast(bfv8, f1u);

    const unsigned short* vp = vfb + (size_t)it * 4096;
    o0 = mfma32(ld8(vp),            pf0, o0);
    o0 = mfma32(ld8(vp + 512),      pf1, o0);
    o1 = mfma32(ld8(vp + 2 * 512),  pf0, o1);
    o1 = mfma32(ld8(vp + 3 * 512),  pf1, o1);
    o2 = mfma32(ld8(vp + 4 * 512),  pf0, o2);
    o2 = mfma32(ld8(vp + 5 * 512),  pf1, o2);
    o3 = mfma32(ld8(vp + 6 * 512),  pf0, o3);
    o3 = mfma32(ld8(vp + 7 * 512),  pf1, o3);
  }

  const float inv = 1.f / l;
  #define EPI(ODT, DT) \
  { \
    _Pragma("unroll") \
    for (int r = 0; r < 16; ++r) \
      Ts[w][c][(r & 3) + 8 * (r >> 2) + 4 * hi] = f2bf(ODT[r] * inv); \
    asm volatile("s_waitcnt lgkmcnt(0)" ::: "memory"); \
    _Pragma("unroll") \
    for (int pz = 0; pz < 2; ++pz){ \
      int qr = (lane >> 2) + pz * 16; \
      int dcol = (lane & 3) * 8; \
      s16v8 val = *reinterpret_cast<const s16v8*>(&Ts[w][qr][dcol]); \
      *reinterpret_cast<s16v8*>(&O[(size_t)(b * SEQL + q0 + qr) * DIMN + h * HD + DT * 32 + dcol]) = val; \
    } \
    asm volatile("s_waitcnt lgkmcnt(0)" ::: "memory"); \
  }
  EPI(o0, 0) EPI(o1, 1) EPI(o2, 2) EPI(o3, 3)
  #undef EPI
}

extern "C" void kernel_launch(void* const* d_in, const int* in_sizes, int n_in,
                              void* d_out, int out_size, void* d_ws, size_t ws_size,
                              hipStream_t stream){
  const float* x  = (const float*)d_in[0];
  const float* fc = (const float*)d_in[1];
  const float* fs = (const float*)d_in[2];
  const float* wq = (const float*)d_in[3];
  const float* wk = (const float*)d_in[4];
  const float* wv = (const float*)d_in[5];
  const float* wo = (const float*)d_in[6];
  float* out = (float*)d_out;
  char* ws = (char*)d_ws;
  unsigned short* xb  = (unsigned short*)(ws);              // 16 MB
  unsigned short* wqb = (unsigned short*)(ws + 16777216);   // 8 MB (reused as Kf after QKV gemms)
  unsigned short* wkb = (unsigned short*)(ws + 25165824);   // 4 MB
  unsigned short* wvb = (unsigned short*)(ws + 29360128);   // 4 MB
  unsigned short* wob = (unsigned short*)(ws + 33554432);   // 8 MB
  unsigned short* Qb  = (unsigned short*)(ws + 41943040);   // 16 MB
  unsigned short* Kb  = (unsigned short*)(ws + 58720256);   // 8 MB
  unsigned short* Vb  = (unsigned short*)(ws + 67108864);   // 8 MB
  unsigned short* Vf  = (unsigned short*)(ws + 75497472);   // 8 MB
  unsigned short* Ab  = (unsigned short*)(ws + 83886080);   // 16 MB
  unsigned short* Kf  = wqb;                                 // reuse wq bf16 slot

  dim3 blk(256);
  cvtk<<<dim3(8192), blk, 0, stream>>>(x,  xb,  2097152);
  cvtk<<<dim3(4096), blk, 0, stream>>>(wq, wqb, 1048576);
  cvtk<<<dim3(2048), blk, 0, stream>>>(wk, wkb, 524288);
  cvtk<<<dim3(2048), blk, 0, stream>>>(wv, wvb, 524288);
  cvtk<<<dim3(4096), blk, 0, stream>>>(wo, wob, 1048576);
  gemm2<false><<<dim3(16, 32), blk, 0, stream>>>(xb, wqb, Qb, 4096, 2048, 2048);
  gemm2<false><<<dim3(8, 32),  blk, 0, stream>>>(xb, wkb, Kb, 4096, 1024, 2048);
  gemm2<false><<<dim3(8, 32),  blk, 0, stream>>>(xb, wvb, Vb, 4096, 1024, 2048);
  ropek<<<dim3(16384), blk, 0, stream>>>(Qb, fc, fs, 2048);
  kswz<<<dim3(64, 16), blk, 0, stream>>>(Kb, fc, fs, Kf);
  vswz<<<dim3(64, 16), blk, 0, stream>>>(Vb, Vf);
  fattn3<<<dim3(1024), dim3(128), 0, stream>>>(Qb, Kf, Vf, Ab);
  gemm2<true><<<dim3(16, 32), blk, 0, stream>>>(Ab, wob, out, 4096, 2048, 2048);
}

// Round 4
// 277.608 us; speedup vs baseline: 2.6731x; 1.1267x over previous
//
#include <hip/hip_runtime.h>
#include <hip/hip_bf16.h>

#define SEQL 2048
#define DIMN 2048
#define NH 16
#define NKV 8
#define HD 128
#define NB 2

typedef float f32v4 __attribute__((ext_vector_type(4)));
typedef float f32v16 __attribute__((ext_vector_type(16)));
typedef __bf16 bfv8 __attribute__((ext_vector_type(8)));
typedef short s16v8 __attribute__((ext_vector_type(8)));
typedef unsigned short u16v4 __attribute__((ext_vector_type(4)));
typedef unsigned int u32v4 __attribute__((ext_vector_type(4)));
typedef int i32v2 __attribute__((ext_vector_type(2)));

__device__ inline unsigned short f2bf(float f){
  union { float f; unsigned u; } v; v.f = f;
  unsigned r = (v.u + 0x7fffu + ((v.u >> 16) & 1u)) >> 16;
  return (unsigned short)r;
}
__device__ inline float bf2f(unsigned short u){
  union { unsigned u; float f; } v; v.u = ((unsigned)u) << 16;
  return v.f;
}
__device__ inline f32v4 mfma16(bfv8 a, bfv8 b, f32v4 c){
  return __builtin_amdgcn_mfma_f32_16x16x32_bf16(a, b, c, 0, 0, 0);
}
__device__ inline f32v16 mfma32(bfv8 a, bfv8 b, f32v16 c){
  return __builtin_amdgcn_mfma_f32_32x32x16_bf16(a, b, c, 0, 0, 0);
}
__device__ inline bfv8 ld8(const unsigned short* p){
  s16v8 v = *reinterpret_cast<const s16v8*>(p);
  return __builtin_bit_cast(bfv8, v);
}
__device__ inline void gload16(const void* g, void* l){
  __builtin_amdgcn_global_load_lds(
      (const __attribute__((address_space(1))) unsigned int*)g,
      (__attribute__((address_space(3))) unsigned int*)l, 16, 0, 0);
}

// ---- fp32 -> bf16 convert (vectorized) ----
__global__ __launch_bounds__(256) void cvtk(const float* __restrict__ in,
                                            unsigned short* __restrict__ out, int n4){
  int i = blockIdx.x * 256 + threadIdx.x;
  if (i >= n4) return;
  const float4 v = reinterpret_cast<const float4*>(in)[i];
  u16v4 w; w[0] = f2bf(v.x); w[1] = f2bf(v.y); w[2] = f2bf(v.z); w[3] = f2bf(v.w);
  reinterpret_cast<u16v4*>(out)[i] = w;
}

// ---- C[M,N] = A[M,K] * B[N,K]^T, m97 structure: global_load_lds staging ----
template<bool CF32>
__global__ __launch_bounds__(256) void gemm2(const unsigned short* __restrict__ A,
                                             const unsigned short* __restrict__ B,
                                             void* __restrict__ Cp,
                                             int M, int N, int K){
  __shared__ unsigned short As[128 * 64];
  __shared__ unsigned short Bs[128 * 64];
  const int tid = threadIdx.x;
  const int lane = tid & 63;
  const int wave = tid >> 6;
  const int wr = (wave >> 1) * 64, wc = (wave & 1) * 64;
  const int bm = blockIdx.y * 128, bn = blockIdx.x * 128;
  const int l15 = lane & 15, lg = lane >> 4;
  const int lr = lane >> 3, lc = (lane & 7) * 8;

  f32v4 acc[4][4] = {};
  for (int kt = 0; kt < K; kt += 64){
    #pragma unroll
    for (int p = 0; p < 4; ++p){
      const int row = p * 32 + wave * 8 + lr;
      const int ldso = p * 2048 + wave * 512;
      gload16(&A[(size_t)(bm + row) * K + kt + lc], &As[ldso]);
      gload16(&B[(size_t)(bn + row) * K + kt + lc], &Bs[ldso]);
    }
    __syncthreads();
    #pragma unroll
    for (int kk = 0; kk < 64; kk += 32){
      bfv8 af[4], bfr[4];
      #pragma unroll
      for (int i = 0; i < 4; ++i) af[i] = ld8(&As[(wr + i * 16 + l15) * 64 + kk + lg * 8]);
      #pragma unroll
      for (int j = 0; j < 4; ++j) bfr[j] = ld8(&Bs[(wc + j * 16 + l15) * 64 + kk + lg * 8]);
      #pragma unroll
      for (int i = 0; i < 4; ++i)
        #pragma unroll
        for (int j = 0; j < 4; ++j)
          acc[i][j] = mfma16(af[i], bfr[j], acc[i][j]);
    }
    __syncthreads();
  }
  #pragma unroll
  for (int i = 0; i < 4; ++i){
    #pragma unroll
    for (int j = 0; j < 4; ++j){
      const int gr = bm + wr + i * 16 + lg * 4;
      const int gc = bn + wc + j * 16 + l15;
      #pragma unroll
      for (int r = 0; r < 4; ++r){
        if (CF32) reinterpret_cast<float*>(Cp)[(size_t)(gr + r) * N + gc] = acc[i][j][r];
        else reinterpret_cast<unsigned short*>(Cp)[(size_t)(gr + r) * N + gc] = f2bf(acc[i][j][r]);
      }
    }
  }
}

// ---- RoPE in-place on bf16 [rows][ncols], with output scale (Q: fold softmax scale) ----
__global__ __launch_bounds__(256) void ropek(unsigned short* __restrict__ T,
                                             const float* __restrict__ fc,
                                             const float* __restrict__ fs, int ncols,
                                             float scale){
  int p = blockIdx.x * 256 + threadIdx.x;
  int half = ncols >> 1;
  int row = p / half;
  int pc = p - row * half;
  int h = pc >> 6, i = pc & 63;
  int s = row & (SEQL - 1);
  size_t idx = (size_t)row * ncols + h * HD + 2 * i;
  float r = bf2f(T[idx]), im = bf2f(T[idx + 1]);
  float c = fc[s * 64 + i], sn = fs[s * 64 + i];
  T[idx]     = f2bf((r * c - im * sn) * scale);
  T[idx + 1] = f2bf((r * sn + im * c) * scale);
}

// ---- K swizzle + fused RoPE: KVb fused [4096][2048] -> Kf fragment-major ----
__global__ __launch_bounds__(256) void kswz(const unsigned short* __restrict__ KVb,
                                            const float* __restrict__ fc,
                                            const float* __restrict__ fs,
                                            unsigned short* __restrict__ Kf){
  __shared__ unsigned short Ks[32][132];
  const int bk = blockIdx.y, kv32 = blockIdx.x;
  const int b = bk >> 3, kvh = bk & 7;
  const int t = threadIdx.x;
  const int r = t >> 3, cc = (t & 7) * 16;
  const int s = kv32 * 32 + r;
  const unsigned short* src = KVb + (size_t)(b * SEQL + s) * 2048 + kvh * HD + cc;
  s16v8 v0 = *reinterpret_cast<const s16v8*>(src);
  s16v8 v1 = *reinterpret_cast<const s16v8*>(src + 8);
  float4 c0 = *reinterpret_cast<const float4*>(&fc[s * 64 + (cc >> 1)]);
  float4 c1 = *reinterpret_cast<const float4*>(&fc[s * 64 + (cc >> 1) + 4]);
  float4 sv0 = *reinterpret_cast<const float4*>(&fs[s * 64 + (cc >> 1)]);
  float4 sv1 = *reinterpret_cast<const float4*>(&fs[s * 64 + (cc >> 1) + 4]);
  float cA[8] = {c0.x, c0.y, c0.z, c0.w, c1.x, c1.y, c1.z, c1.w};
  float sA[8] = {sv0.x, sv0.y, sv0.z, sv0.w, sv1.x, sv1.y, sv1.z, sv1.w};
  unsigned short e[16];
  #pragma unroll
  for (int k = 0; k < 8; ++k){ e[k] = (unsigned short)v0[k]; e[k + 8] = (unsigned short)v1[k]; }
  #pragma unroll
  for (int pi = 0; pi < 8; ++pi){
    float re = bf2f(e[2 * pi]), im = bf2f(e[2 * pi + 1]);
    Ks[r][cc + 2 * pi]     = f2bf(re * cA[pi] - im * sA[pi]);
    Ks[r][cc + 2 * pi + 1] = f2bf(re * sA[pi] + im * cA[pi]);
  }
  __syncthreads();
  const int l = t & 63;
  #pragma unroll
  for (int p = 0; p < 2; ++p){
    int ds = (t >> 6) * 2 + p;
    s16v8 val = *reinterpret_cast<const s16v8*>(&Ks[l & 31][ds * 16 + (l >> 5) * 8]);
    *reinterpret_cast<s16v8*>(&Kf[(((size_t)bk * 64 + kv32) * 8 + ds) * 512 + (size_t)l * 8]) = val;
  }
}

// ---- V swizzle: KVb fused (V at col 1024) -> Vf fragment-major ----
__global__ __launch_bounds__(256) void vswz(const unsigned short* __restrict__ KVb,
                                            unsigned short* __restrict__ Vf){
  __shared__ unsigned short Vs[32][132];
  const int bk = blockIdx.y, kv32 = blockIdx.x;
  const int b = bk >> 3, kvh = bk & 7;
  const int t = threadIdx.x;
  const int r = t >> 3, cc = (t & 7) * 16;
  const int s = kv32 * 32 + r;
  const unsigned short* src = KVb + (size_t)(b * SEQL + s) * 2048 + 1024 + kvh * HD + cc;
  *reinterpret_cast<s16v8*>(&Vs[r][cc])     = *reinterpret_cast<const s16v8*>(src);
  *reinterpret_cast<s16v8*>(&Vs[r][cc + 8]) = *reinterpret_cast<const s16v8*>(src + 8);
  __syncthreads();
  const int dt = t >> 6, l = t & 63;
  #pragma unroll
  for (int h2 = 0; h2 < 2; ++h2){
    s16v8 val;
    #pragma unroll
    for (int j = 0; j < 8; ++j)
      val[j] = (short)Vs[h2 * 16 + (l >> 5) * 8 + j][dt * 32 + (l & 31)];
    *reinterpret_cast<s16v8*>(&Vf[(((size_t)bk * 64 + kv32) * 8 + dt * 2 + h2) * 512 + (size_t)l * 8]) = val;
  }
}

// ---- flash attention, causal, GQA(2): swapped 32x32, fragment-major K/V ----
// 1 wave / block, 32 q-rows per wave. Q pre-scaled by softmax_scale*log2e.
__global__ __launch_bounds__(64) void fattn4(const unsigned short* __restrict__ Q,
                                             const unsigned short* __restrict__ Kf,
                                             const unsigned short* __restrict__ Vf,
                                             unsigned short* __restrict__ O){
  __shared__ __align__(16) unsigned short Ts[32][40];
  const int id = blockIdx.x;
  const int xcd = id & 7, sub = (id >> 3) & 3;
  const int bh = xcd * 4 + sub;
  const int qi = 63 - (id >> 5);            // heavy q-tiles dispatch first
  const int b = bh >> 4, h = bh & 15, kvh = h >> 1;
  const int bk = b * NKV + kvh;
  const int lane = threadIdx.x;
  const int c = lane & 31, hi = lane >> 5;
  const int q0 = qi * 32;
  const int q = q0 + c;

  bfv8 qf[8];
  {
    const unsigned short* qp = Q + (size_t)(b * SEQL + q) * DIMN + h * HD + hi * 8;
    #pragma unroll
    for (int ds = 0; ds < 8; ++ds) qf[ds] = ld8(qp + ds * 16);
  }

  f32v16 o0 = {}, o1 = {}, o2 = {}, o3 = {};
  float m = -1e30f, l = 0.f;

  const unsigned short* kfb = Kf + ((size_t)bk * 64) * 4096 + (size_t)lane * 8;
  const unsigned short* vfb = Vf + ((size_t)bk * 64) * 4096 + (size_t)lane * 8;

  bfv8 kf[8];
  #pragma unroll
  for (int ds = 0; ds < 8; ++ds) kf[ds] = ld8(kfb + ds * 512);

#define AITER(MASKED, PREF, IT) { \
    f32v16 s = {}; \
    __builtin_amdgcn_s_setprio(1); \
    _Pragma("unroll") \
    for (int ds = 0; ds < 8; ++ds) s = mfma32(kf[ds], qf[ds], s); \
    __builtin_amdgcn_s_setprio(0); \
    if (PREF){ \
      const unsigned short* kn = kfb + (size_t)((IT) + 1) * 4096; \
      _Pragma("unroll") \
      for (int ds = 0; ds < 8; ++ds) kf[ds] = ld8(kn + ds * 512); \
    } \
    float t[16]; \
    _Pragma("unroll") \
    for (int r = 0; r < 16; ++r){ \
      t[r] = s[r]; \
      if (MASKED && ((r & 3) + 8 * (r >> 2) + 4 * hi) > c) t[r] = -3.0e38f; \
    } \
    float mx = t[0]; \
    _Pragma("unroll") \
    for (int r = 1; r < 16; ++r) mx = fmaxf(mx, t[r]); \
    mx = fmaxf(mx, __shfl_xor(mx, 32)); \
    if (!__all(mx - m <= 8.f)){ \
      float mn = fmaxf(m, mx); \
      float corr = __builtin_exp2f(m - mn); \
      l *= corr; \
      _Pragma("unroll") \
      for (int r = 0; r < 16; ++r){ o0[r]*=corr; o1[r]*=corr; o2[r]*=corr; o3[r]*=corr; } \
      m = mn; \
    } \
    float p[16], lsum = 0.f; \
    _Pragma("unroll") \
    for (int r = 0; r < 16; ++r){ p[r] = __builtin_exp2f(t[r] - m); lsum += p[r]; } \
    lsum += __shfl_xor(lsum, 32); \
    l += lsum; \
    unsigned w32[8]; \
    _Pragma("unroll") \
    for (int i = 0; i < 8; ++i){ \
      unsigned short lo_ = __builtin_bit_cast(unsigned short, (__bf16)p[2*i]); \
      unsigned short hb_ = __builtin_bit_cast(unsigned short, (__bf16)p[2*i+1]); \
      w32[i] = (unsigned)lo_ | ((unsigned)hb_ << 16); \
    } \
    i32v2 r0_ = __builtin_amdgcn_permlane32_swap((int)w32[0], (int)w32[2], false, false); \
    i32v2 r1_ = __builtin_amdgcn_permlane32_swap((int)w32[1], (int)w32[3], false, false); \
    i32v2 r2_ = __builtin_amdgcn_permlane32_swap((int)w32[4], (int)w32[6], false, false); \
    i32v2 r3_ = __builtin_amdgcn_permlane32_swap((int)w32[5], (int)w32[7], false, false); \
    u32v4 f0u, f1u; \
    f0u[0] = (unsigned)r0_[0]; f0u[1] = (unsigned)r1_[0]; \
    f0u[2] = (unsigned)r0_[1]; f0u[3] = (unsigned)r1_[1]; \
    f1u[0] = (unsigned)r2_[0]; f1u[1] = (unsigned)r3_[0]; \
    f1u[2] = (unsigned)r2_[1]; f1u[3] = (unsigned)r3_[1]; \
    bfv8 pf0 = __builtin_bit_cast(bfv8, f0u); \
    bfv8 pf1 = __builtin_bit_cast(bfv8, f1u); \
    const unsigned short* vp = vfb + (size_t)(IT) * 4096; \
    __builtin_amdgcn_s_setprio(1); \
    o0 = mfma32(ld8(vp),        pf0, o0); \
    o0 = mfma32(ld8(vp + 512),  pf1, o0); \
    o1 = mfma32(ld8(vp + 1024), pf0, o1); \
    o1 = mfma32(ld8(vp + 1536), pf1, o1); \
    o2 = mfma32(ld8(vp + 2048), pf0, o2); \
    o2 = mfma32(ld8(vp + 2560), pf1, o2); \
    o3 = mfma32(ld8(vp + 3072), pf0, o3); \
    o3 = mfma32(ld8(vp + 3584), pf1, o3); \
    __builtin_amdgcn_s_setprio(0); \
  }

  for (int it = 0; it < qi; ++it){
    AITER(false, true, it)
  }
  AITER(true, false, qi)
#undef AITER

  const float inv = 1.f / l;
  #define EPI(ODT, DT) \
  { \
    _Pragma("unroll") \
    for (int r = 0; r < 16; ++r) \
      Ts[c][(r & 3) + 8 * (r >> 2) + 4 * hi] = f2bf(ODT[r] * inv); \
    asm volatile("s_waitcnt lgkmcnt(0)" ::: "memory"); \
    _Pragma("unroll") \
    for (int pz = 0; pz < 2; ++pz){ \
      int qr = (lane >> 2) + pz * 16; \
      int dcol = (lane & 3) * 8; \
      s16v8 val = *reinterpret_cast<const s16v8*>(&Ts[qr][dcol]); \
      *reinterpret_cast<s16v8*>(&O[(size_t)(b * SEQL + q0 + qr) * DIMN + h * HD + DT * 32 + dcol]) = val; \
    } \
    asm volatile("s_waitcnt lgkmcnt(0)" ::: "memory"); \
  }
  EPI(o0, 0) EPI(o1, 1) EPI(o2, 2) EPI(o3, 3)
  #undef EPI
}

extern "C" void kernel_launch(void* const* d_in, const int* in_sizes, int n_in,
                              void* d_out, int out_size, void* d_ws, size_t ws_size,
                              hipStream_t stream){
  const float* x  = (const float*)d_in[0];
  const float* fc = (const float*)d_in[1];
  const float* fs = (const float*)d_in[2];
  const float* wq = (const float*)d_in[3];
  const float* wk = (const float*)d_in[4];
  const float* wv = (const float*)d_in[5];
  const float* wo = (const float*)d_in[6];
  float* out = (float*)d_out;
  char* ws = (char*)d_ws;
  unsigned short* xb  = (unsigned short*)(ws);              // 16 MB
  unsigned short* wqb = (unsigned short*)(ws + 16777216);   // 8 MB (reused as Kf)
  unsigned short* wkb = (unsigned short*)(ws + 25165824);   // 4 MB (wk; wv adjacent)
  unsigned short* wvb = (unsigned short*)(ws + 29360128);   // 4 MB
  unsigned short* wob = (unsigned short*)(ws + 33554432);   // 8 MB
  unsigned short* Qb  = (unsigned short*)(ws + 41943040);   // 16 MB
  unsigned short* KVb = (unsigned short*)(ws + 58720256);   // 16 MB fused [4096][2048]
  unsigned short* Vf  = (unsigned short*)(ws + 75497472);   // 8 MB
  unsigned short* Ab  = (unsigned short*)(ws + 83886080);   // 16 MB
  unsigned short* Kf  = wqb;                                 // reuse wq bf16 slot

  const float c1 = 0.08838834764831845f * 1.4426950408889634f;

  dim3 blk(256);
  cvtk<<<dim3(8192), blk, 0, stream>>>(x,  xb,  2097152);
  cvtk<<<dim3(4096), blk, 0, stream>>>(wq, wqb, 1048576);
  cvtk<<<dim3(2048), blk, 0, stream>>>(wk, wkb, 524288);
  cvtk<<<dim3(2048), blk, 0, stream>>>(wv, wvb, 524288);
  cvtk<<<dim3(4096), blk, 0, stream>>>(wo, wob, 1048576);
  gemm2<false><<<dim3(16, 32), blk, 0, stream>>>(xb, wqb, Qb, 4096, 2048, 2048);
  gemm2<false><<<dim3(16, 32), blk, 0, stream>>>(xb, wkb, KVb, 4096, 2048, 2048);
  ropek<<<dim3(16384), blk, 0, stream>>>(Qb, fc, fs, 2048, c1);
  kswz<<<dim3(64, 16), blk, 0, stream>>>(KVb, fc, fs, Kf);
  vswz<<<dim3(64, 16), blk, 0, stream>>>(KVb, Vf);
  fattn4<<<dim3(2048), dim3(64), 0, stream>>>(Qb, Kf, Vf, Ab);
  gemm2<true><<<dim3(16, 32), blk, 0, stream>>>(Ab, wob, out, 4096, 2048, 2048);
}

// Round 5
// 253.371 us; speedup vs baseline: 2.9288x; 1.0957x over previous
//
#include <hip/hip_runtime.h>
#include <hip/hip_bf16.h>

#define SEQL 2048
#define DIMN 2048
#define NH 16
#define NKV 8
#define HD 128
#define NB 2

typedef float f32v4 __attribute__((ext_vector_type(4)));
typedef float f32v16 __attribute__((ext_vector_type(16)));
typedef __bf16 bfv8 __attribute__((ext_vector_type(8)));
typedef short s16v8 __attribute__((ext_vector_type(8)));
typedef unsigned short u16v4 __attribute__((ext_vector_type(4)));
typedef unsigned int u32v4 __attribute__((ext_vector_type(4)));
typedef int i32v2 __attribute__((ext_vector_type(2)));

__device__ inline unsigned short f2bf(float f){
  union { float f; unsigned u; } v; v.f = f;
  unsigned r = (v.u + 0x7fffu + ((v.u >> 16) & 1u)) >> 16;
  return (unsigned short)r;
}
__device__ inline float bf2f(unsigned short u){
  union { unsigned u; float f; } v; v.u = ((unsigned)u) << 16;
  return v.f;
}
__device__ inline f32v4 mfma16(bfv8 a, bfv8 b, f32v4 c){
  return __builtin_amdgcn_mfma_f32_16x16x32_bf16(a, b, c, 0, 0, 0);
}
__device__ inline f32v16 mfma32(bfv8 a, bfv8 b, f32v16 c){
  return __builtin_amdgcn_mfma_f32_32x32x16_bf16(a, b, c, 0, 0, 0);
}
__device__ inline bfv8 ld8(const unsigned short* p){
  s16v8 v = *reinterpret_cast<const s16v8*>(p);
  return __builtin_bit_cast(bfv8, v);
}
__device__ inline void gload16(const void* g, void* l){
  __builtin_amdgcn_global_load_lds(
      (const __attribute__((address_space(1))) unsigned int*)g,
      (__attribute__((address_space(3))) unsigned int*)l, 16, 0, 0);
}

// ---- fp32 -> bf16 convert (vectorized) ----
__global__ __launch_bounds__(256) void cvtk(const float* __restrict__ in,
                                            unsigned short* __restrict__ out, int n4){
  int i = blockIdx.x * 256 + threadIdx.x;
  if (i >= n4) return;
  const float4 v = reinterpret_cast<const float4*>(in)[i];
  u16v4 w; w[0] = f2bf(v.x); w[1] = f2bf(v.y); w[2] = f2bf(v.z); w[3] = f2bf(v.w);
  reinterpret_cast<u16v4*>(out)[i] = w;
}

// ---- C[M,N] = A[M,K] * B[N,K]^T, m97 structure: global_load_lds staging ----
template<bool CF32>
__global__ __launch_bounds__(256) void gemm2(const unsigned short* __restrict__ A,
                                             const unsigned short* __restrict__ B,
                                             void* __restrict__ Cp,
                                             int M, int N, int K){
  __shared__ unsigned short As[128 * 64];
  __shared__ unsigned short Bs[128 * 64];
  const int tid = threadIdx.x;
  const int lane = tid & 63;
  const int wave = tid >> 6;
  const int wr = (wave >> 1) * 64, wc = (wave & 1) * 64;
  const int bm = blockIdx.y * 128, bn = blockIdx.x * 128;
  const int l15 = lane & 15, lg = lane >> 4;
  const int lr = lane >> 3, lc = (lane & 7) * 8;

  f32v4 acc[4][4] = {};
  for (int kt = 0; kt < K; kt += 64){
    #pragma unroll
    for (int p = 0; p < 4; ++p){
      const int row = p * 32 + wave * 8 + lr;
      const int ldso = p * 2048 + wave * 512;
      gload16(&A[(size_t)(bm + row) * K + kt + lc], &As[ldso]);
      gload16(&B[(size_t)(bn + row) * K + kt + lc], &Bs[ldso]);
    }
    __syncthreads();
    #pragma unroll
    for (int kk = 0; kk < 64; kk += 32){
      bfv8 af[4], bfr[4];
      #pragma unroll
      for (int i = 0; i < 4; ++i) af[i] = ld8(&As[(wr + i * 16 + l15) * 64 + kk + lg * 8]);
      #pragma unroll
      for (int j = 0; j < 4; ++j) bfr[j] = ld8(&Bs[(wc + j * 16 + l15) * 64 + kk + lg * 8]);
      #pragma unroll
      for (int i = 0; i < 4; ++i)
        #pragma unroll
        for (int j = 0; j < 4; ++j)
          acc[i][j] = mfma16(af[i], bfr[j], acc[i][j]);
    }
    __syncthreads();
  }
  #pragma unroll
  for (int i = 0; i < 4; ++i){
    #pragma unroll
    for (int j = 0; j < 4; ++j){
      const int gr = bm + wr + i * 16 + lg * 4;
      const int gc = bn + wc + j * 16 + l15;
      #pragma unroll
      for (int r = 0; r < 4; ++r){
        if (CF32) reinterpret_cast<float*>(Cp)[(size_t)(gr + r) * N + gc] = acc[i][j][r];
        else reinterpret_cast<unsigned short*>(Cp)[(size_t)(gr + r) * N + gc] = f2bf(acc[i][j][r]);
      }
    }
  }
}

// ---- RoPE in-place on bf16 [rows][stride], rope'd cols 0..ncols-1, scaled ----
__global__ __launch_bounds__(256) void ropek(unsigned short* __restrict__ T,
                                             const float* __restrict__ fc,
                                             const float* __restrict__ fs, int ncols,
                                             int stride, float scale){
  int p = blockIdx.x * 256 + threadIdx.x;
  int half = ncols >> 1;
  int row = p / half;
  int pc = p - row * half;
  int h = pc >> 6, i = pc & 63;
  int s = row & (SEQL - 1);
  size_t idx = (size_t)row * stride + h * HD + 2 * i;
  float r = bf2f(T[idx]), im = bf2f(T[idx + 1]);
  float c = fc[s * 64 + i], sn = fs[s * 64 + i];
  T[idx]     = f2bf((r * c - im * sn) * scale);
  T[idx + 1] = f2bf((r * sn + im * c) * scale);
}

// ---- K swizzle + fused RoPE: QKVb fused [4096][4096] (K at col 2048) -> Kf ----
__global__ __launch_bounds__(256) void kswz(const unsigned short* __restrict__ QKVb,
                                            const float* __restrict__ fc,
                                            const float* __restrict__ fs,
                                            unsigned short* __restrict__ Kf){
  __shared__ unsigned short Ks[32][132];
  const int bk = blockIdx.y, kv32 = blockIdx.x;
  const int b = bk >> 3, kvh = bk & 7;
  const int t = threadIdx.x;
  const int r = t >> 3, cc = (t & 7) * 16;
  const int s = kv32 * 32 + r;
  const unsigned short* src = QKVb + (size_t)(b * SEQL + s) * 4096 + 2048 + kvh * HD + cc;
  s16v8 v0 = *reinterpret_cast<const s16v8*>(src);
  s16v8 v1 = *reinterpret_cast<const s16v8*>(src + 8);
  float4 c0 = *reinterpret_cast<const float4*>(&fc[s * 64 + (cc >> 1)]);
  float4 c1 = *reinterpret_cast<const float4*>(&fc[s * 64 + (cc >> 1) + 4]);
  float4 sv0 = *reinterpret_cast<const float4*>(&fs[s * 64 + (cc >> 1)]);
  float4 sv1 = *reinterpret_cast<const float4*>(&fs[s * 64 + (cc >> 1) + 4]);
  float cA[8] = {c0.x, c0.y, c0.z, c0.w, c1.x, c1.y, c1.z, c1.w};
  float sA[8] = {sv0.x, sv0.y, sv0.z, sv0.w, sv1.x, sv1.y, sv1.z, sv1.w};
  unsigned short e[16];
  #pragma unroll
  for (int k = 0; k < 8; ++k){ e[k] = (unsigned short)v0[k]; e[k + 8] = (unsigned short)v1[k]; }
  #pragma unroll
  for (int pi = 0; pi < 8; ++pi){
    float re = bf2f(e[2 * pi]), im = bf2f(e[2 * pi + 1]);
    Ks[r][cc + 2 * pi]     = f2bf(re * cA[pi] - im * sA[pi]);
    Ks[r][cc + 2 * pi + 1] = f2bf(re * sA[pi] + im * cA[pi]);
  }
  __syncthreads();
  const int l = t & 63;
  #pragma unroll
  for (int p = 0; p < 2; ++p){
    int ds = (t >> 6) * 2 + p;
    s16v8 val = *reinterpret_cast<const s16v8*>(&Ks[l & 31][ds * 16 + (l >> 5) * 8]);
    *reinterpret_cast<s16v8*>(&Kf[(((size_t)bk * 64 + kv32) * 8 + ds) * 512 + (size_t)l * 8]) = val;
  }
}

// ---- V swizzle: QKVb fused (V at col 3072) -> Vf fragment-major ----
__global__ __launch_bounds__(256) void vswz(const unsigned short* __restrict__ QKVb,
                                            unsigned short* __restrict__ Vf){
  __shared__ unsigned short Vs[32][132];
  const int bk = blockIdx.y, kv32 = blockIdx.x;
  const int b = bk >> 3, kvh = bk & 7;
  const int t = threadIdx.x;
  const int r = t >> 3, cc = (t & 7) * 16;
  const int s = kv32 * 32 + r;
  const unsigned short* src = QKVb + (size_t)(b * SEQL + s) * 4096 + 3072 + kvh * HD + cc;
  *reinterpret_cast<s16v8*>(&Vs[r][cc])     = *reinterpret_cast<const s16v8*>(src);
  *reinterpret_cast<s16v8*>(&Vs[r][cc + 8]) = *reinterpret_cast<const s16v8*>(src + 8);
  __syncthreads();
  const int dt = t >> 6, l = t & 63;
  #pragma unroll
  for (int h2 = 0; h2 < 2; ++h2){
    s16v8 val;
    #pragma unroll
    for (int j = 0; j < 8; ++j)
      val[j] = (short)Vs[h2 * 16 + (l >> 5) * 8 + j][dt * 32 + (l & 31)];
    *reinterpret_cast<s16v8*>(&Vf[(((size_t)bk * 64 + kv32) * 8 + dt * 2 + h2) * 512 + (size_t)l * 8]) = val;
  }
}

// ---- flash attention, causal, GQA(2): swapped 32x32, fragment-major K/V ----
// 1 wave / block, 32 q-rows. Q pre-scaled by softmax_scale*log2e (stride 4096).
// ILP: V preloaded at top of iter; QK split into 2 independent MFMA chains.
__global__ __launch_bounds__(64) void fattn5(const unsigned short* __restrict__ Q,
                                             const unsigned short* __restrict__ Kf,
                                             const unsigned short* __restrict__ Vf,
                                             unsigned short* __restrict__ O){
  __shared__ __align__(16) unsigned short Ts[32][40];
  const int id = blockIdx.x;
  const int xcd = id & 7, sub = (id >> 3) & 3;
  const int bh = xcd * 4 + sub;
  const int qi = 63 - (id >> 5);            // heavy q-tiles dispatch first
  const int b = bh >> 4, h = bh & 15, kvh = h >> 1;
  const int bk = b * NKV + kvh;
  const int lane = threadIdx.x;
  const int c = lane & 31, hi = lane >> 5;
  const int q0 = qi * 32;
  const int q = q0 + c;

  bfv8 qf[8];
  {
    const unsigned short* qp = Q + (size_t)(b * SEQL + q) * 4096 + h * HD + hi * 8;
    #pragma unroll
    for (int ds = 0; ds < 8; ++ds) qf[ds] = ld8(qp + ds * 16);
  }

  f32v16 o0 = {}, o1 = {}, o2 = {}, o3 = {};
  float m = -1e30f, l = 0.f;

  const unsigned short* kfb = Kf + ((size_t)bk * 64) * 4096 + (size_t)lane * 8;
  const unsigned short* vfb = Vf + ((size_t)bk * 64) * 4096 + (size_t)lane * 8;

  bfv8 kf[8];
  #pragma unroll
  for (int ds = 0; ds < 8; ++ds) kf[ds] = ld8(kfb + ds * 512);

#define AITER(MASKED, PREF, IT) { \
    /* V preload for this tile: lands under QK + softmax */ \
    const unsigned short* vp = vfb + (size_t)(IT) * 4096; \
    bfv8 vf[8]; \
    _Pragma("unroll") \
    for (int dv = 0; dv < 8; ++dv) vf[dv] = ld8(vp + dv * 512); \
    f32v16 sa = {}, sb = {}; \
    __builtin_amdgcn_s_setprio(1); \
    _Pragma("unroll") \
    for (int ds = 0; ds < 4; ++ds){ \
      sa = mfma32(kf[ds], qf[ds], sa); \
      sb = mfma32(kf[ds + 4], qf[ds + 4], sb); \
    } \
    __builtin_amdgcn_s_setprio(0); \
    if (PREF){ \
      const unsigned short* kn = kfb + (size_t)((IT) + 1) * 4096; \
      _Pragma("unroll") \
      for (int ds = 0; ds < 8; ++ds) kf[ds] = ld8(kn + ds * 512); \
    } \
    float t[16]; \
    _Pragma("unroll") \
    for (int r = 0; r < 16; ++r){ \
      t[r] = sa[r] + sb[r]; \
      if (MASKED && ((r & 3) + 8 * (r >> 2) + 4 * hi) > c) t[r] = -3.0e38f; \
    } \
    float mx = t[0]; \
    _Pragma("unroll") \
    for (int r = 1; r < 16; ++r) mx = fmaxf(mx, t[r]); \
    mx = fmaxf(mx, __shfl_xor(mx, 32)); \
    if (!__all(mx - m <= 8.f)){ \
      float mn = fmaxf(m, mx); \
      float corr = __builtin_exp2f(m - mn); \
      l *= corr; \
      _Pragma("unroll") \
      for (int r = 0; r < 16; ++r){ o0[r]*=corr; o1[r]*=corr; o2[r]*=corr; o3[r]*=corr; } \
      m = mn; \
    } \
    float p[16], lsum = 0.f; \
    _Pragma("unroll") \
    for (int r = 0; r < 16; ++r){ p[r] = __builtin_exp2f(t[r] - m); lsum += p[r]; } \
    lsum += __shfl_xor(lsum, 32); \
    l += lsum; \
    unsigned w32[8]; \
    _Pragma("unroll") \
    for (int i = 0; i < 8; ++i){ \
      unsigned short lo_ = __builtin_bit_cast(unsigned short, (__bf16)p[2*i]); \
      unsigned short hb_ = __builtin_bit_cast(unsigned short, (__bf16)p[2*i+1]); \
      w32[i] = (unsigned)lo_ | ((unsigned)hb_ << 16); \
    } \
    i32v2 r0_ = __builtin_amdgcn_permlane32_swap((int)w32[0], (int)w32[2], false, false); \
    i32v2 r1_ = __builtin_amdgcn_permlane32_swap((int)w32[1], (int)w32[3], false, false); \
    i32v2 r2_ = __builtin_amdgcn_permlane32_swap((int)w32[4], (int)w32[6], false, false); \
    i32v2 r3_ = __builtin_amdgcn_permlane32_swap((int)w32[5], (int)w32[7], false, false); \
    u32v4 f0u, f1u; \
    f0u[0] = (unsigned)r0_[0]; f0u[1] = (unsigned)r1_[0]; \
    f0u[2] = (unsigned)r0_[1]; f0u[3] = (unsigned)r1_[1]; \
    f1u[0] = (unsigned)r2_[0]; f1u[1] = (unsigned)r3_[0]; \
    f1u[2] = (unsigned)r2_[1]; f1u[3] = (unsigned)r3_[1]; \
    bfv8 pf0 = __builtin_bit_cast(bfv8, f0u); \
    bfv8 pf1 = __builtin_bit_cast(bfv8, f1u); \
    __builtin_amdgcn_s_setprio(1); \
    o0 = mfma32(vf[0], pf0, o0); \
    o0 = mfma32(vf[1], pf1, o0); \
    o1 = mfma32(vf[2], pf0, o1); \
    o1 = mfma32(vf[3], pf1, o1); \
    o2 = mfma32(vf[4], pf0, o2); \
    o2 = mfma32(vf[5], pf1, o2); \
    o3 = mfma32(vf[6], pf0, o3); \
    o3 = mfma32(vf[7], pf1, o3); \
    __builtin_amdgcn_s_setprio(0); \
  }

  for (int it = 0; it < qi; ++it){
    AITER(false, true, it)
  }
  AITER(true, false, qi)
#undef AITER

  const float inv = 1.f / l;
  #define EPI(ODT, DT) \
  { \
    _Pragma("unroll") \
    for (int r = 0; r < 16; ++r) \
      Ts[c][(r & 3) + 8 * (r >> 2) + 4 * hi] = f2bf(ODT[r] * inv); \
    asm volatile("s_waitcnt lgkmcnt(0)" ::: "memory"); \
    _Pragma("unroll") \
    for (int pz = 0; pz < 2; ++pz){ \
      int qr = (lane >> 2) + pz * 16; \
      int dcol = (lane & 3) * 8; \
      s16v8 val = *reinterpret_cast<const s16v8*>(&Ts[qr][dcol]); \
      *reinterpret_cast<s16v8*>(&O[(size_t)(b * SEQL + q0 + qr) * DIMN + h * HD + DT * 32 + dcol]) = val; \
    } \
    asm volatile("s_waitcnt lgkmcnt(0)" ::: "memory"); \
  }
  EPI(o0, 0) EPI(o1, 1) EPI(o2, 2) EPI(o3, 3)
  #undef EPI
}

extern "C" void kernel_launch(void* const* d_in, const int* in_sizes, int n_in,
                              void* d_out, int out_size, void* d_ws, size_t ws_size,
                              hipStream_t stream){
  const float* x  = (const float*)d_in[0];
  const float* fc = (const float*)d_in[1];
  const float* fs = (const float*)d_in[2];
  const float* wq = (const float*)d_in[3];
  const float* wk = (const float*)d_in[4];
  const float* wv = (const float*)d_in[5];
  const float* wo = (const float*)d_in[6];
  float* out = (float*)d_out;
  char* ws = (char*)d_ws;
  unsigned short* xb   = (unsigned short*)(ws);              // 16 MB
  unsigned short* wqkv = (unsigned short*)(ws + 16777216);   // 16 MB fused [4096][2048] weights
  unsigned short* wkb  = (unsigned short*)(ws + 25165824);   //   (wk part, +4 MB)
  unsigned short* wvb  = (unsigned short*)(ws + 29360128);   //   (wv part, +4 MB)
  unsigned short* wob  = (unsigned short*)(ws + 33554432);   // 8 MB
  unsigned short* QKVb = (unsigned short*)(ws + 41943040);   // 32 MB fused [4096][4096]
  unsigned short* Ab   = (unsigned short*)(ws + 75497472);   // 16 MB
  unsigned short* Kf   = wqkv;                               // reuse weight slot (8 MB)
  unsigned short* Vf   = wkb;                                // reuse weight slot (8 MB)

  const float c1 = 0.08838834764831845f * 1.4426950408889634f;

  dim3 blk(256);
  cvtk<<<dim3(8192), blk, 0, stream>>>(x,  xb,  2097152);
  cvtk<<<dim3(4096), blk, 0, stream>>>(wq, wqkv, 1048576);
  cvtk<<<dim3(2048), blk, 0, stream>>>(wk, wkb,  524288);
  cvtk<<<dim3(2048), blk, 0, stream>>>(wv, wvb,  524288);
  cvtk<<<dim3(4096), blk, 0, stream>>>(wo, wob,  1048576);
  // fused QKV projection: [4096 tokens] x [4096 out] = Q | K | V
  gemm2<false><<<dim3(32, 32), blk, 0, stream>>>(xb, wqkv, QKVb, 4096, 4096, 2048);
  ropek<<<dim3(16384), blk, 0, stream>>>(QKVb, fc, fs, 2048, 4096, c1);
  kswz<<<dim3(64, 16), blk, 0, stream>>>(QKVb, fc, fs, Kf);
  vswz<<<dim3(64, 16), blk, 0, stream>>>(QKVb, Vf);
  fattn5<<<dim3(2048), dim3(64), 0, stream>>>(QKVb, Kf, Vf, Ab);
  gemm2<true><<<dim3(16, 32), blk, 0, stream>>>(Ab, wob, out, 4096, 2048, 2048);
}

// Round 6
// 225.744 us; speedup vs baseline: 3.2873x; 1.1224x over previous
//
#include <hip/hip_runtime.h>
#include <hip/hip_bf16.h>

#define SEQL 2048
#define DIMN 2048
#define NH 16
#define NKV 8
#define HD 128
#define NB 2

typedef float f32v4 __attribute__((ext_vector_type(4)));
typedef float f32v16 __attribute__((ext_vector_type(16)));
typedef __bf16 bfv8 __attribute__((ext_vector_type(8)));
typedef short s16v8 __attribute__((ext_vector_type(8)));
typedef unsigned short u16v4 __attribute__((ext_vector_type(4)));
typedef unsigned int u32v4 __attribute__((ext_vector_type(4)));
typedef int i32v2 __attribute__((ext_vector_type(2)));

__device__ inline unsigned short f2bf(float f){
  union { float f; unsigned u; } v; v.f = f;
  unsigned r = (v.u + 0x7fffu + ((v.u >> 16) & 1u)) >> 16;
  return (unsigned short)r;
}
__device__ inline float bf2f(unsigned short u){
  union { unsigned u; float f; } v; v.u = ((unsigned)u) << 16;
  return v.f;
}
__device__ inline f32v4 mfma16(bfv8 a, bfv8 b, f32v4 c){
  return __builtin_amdgcn_mfma_f32_16x16x32_bf16(a, b, c, 0, 0, 0);
}
__device__ inline f32v16 mfma32(bfv8 a, bfv8 b, f32v16 c){
  return __builtin_amdgcn_mfma_f32_32x32x16_bf16(a, b, c, 0, 0, 0);
}
__device__ inline bfv8 ld8(const unsigned short* p){
  s16v8 v = *reinterpret_cast<const s16v8*>(p);
  return __builtin_bit_cast(bfv8, v);
}
__device__ inline void gload16(const void* g, void* l){
  __builtin_amdgcn_global_load_lds(
      (const __attribute__((address_space(1))) unsigned int*)g,
      (__attribute__((address_space(3))) unsigned int*)l, 16, 0, 0);
}

// ---- fp32 -> bf16 convert (vectorized) ----
__global__ __launch_bounds__(256) void cvtk(const float* __restrict__ in,
                                            unsigned short* __restrict__ out, int n4){
  int i = blockIdx.x * 256 + threadIdx.x;
  if (i >= n4) return;
  const float4 v = reinterpret_cast<const float4*>(in)[i];
  u16v4 w; w[0] = f2bf(v.x); w[1] = f2bf(v.y); w[2] = f2bf(v.z); w[3] = f2bf(v.w);
  reinterpret_cast<u16v4*>(out)[i] = w;
}

// ---- deep-pipelined 256x256 GEMM: C = A * B^T, bf16 out ----
// BK=32, 4-slot LDS ring, counted vmcnt (T4), read-side XOR swizzle (T2),
// raw s_barrier, setprio around MFMA (T5). 512 thr = 8 waves (2M x 4N).
__global__ __launch_bounds__(512, 2) void gemm3(const unsigned short* __restrict__ A,
                                                const unsigned short* __restrict__ B,
                                                unsigned short* __restrict__ Cp,
                                                int M, int N, int K){
  __shared__ unsigned short lds[65536];   // 4 slots x (A 8192 + B 8192) elems = 128 KB
  const int tid = threadIdx.x;
  const int lane = tid & 63, w = tid >> 6;
  const int wm = w >> 2, wn = w & 3;
  const int nbx = N >> 8;
  const int nwg = gridDim.x;
  const int cpx = nwg >> 3;
  const int id = blockIdx.x;
  const int swz = (id & 7) * cpx + (id >> 3);   // XCD-affine (nwg % 8 == 0)
  const int bm = (swz / nbx) * 256, bn = (swz % nbx) * 256;
  const int l15 = lane & 15, lg = lane >> 4;
  // staging: row = round*128 + w*16 + (lane>>2); colblock = (lane&3) ^ ((lane>>3)&3)
  const int srow = w * 16 + (lane >> 2);
  const int cbg = ((lane & 3) ^ ((lane >> 3) & 3)) * 8;
  // read-side swizzled column (elems): (lg ^ ((l15>>1)&3)) * 8
  const int cbA = (lg ^ ((l15 >> 1) & 3)) * 8;

#define STAGE3(T) { \
    const int kt_ = (T) * 32; \
    const int sl_ = ((T) & 3) * 16384; \
    const unsigned short* ga_ = &A[(size_t)(bm + srow) * K + kt_ + cbg]; \
    const unsigned short* gb_ = &B[(size_t)(bn + srow) * K + kt_ + cbg]; \
    gload16(ga_,                    &lds[sl_ + w * 512]); \
    gload16(ga_ + (size_t)128 * K,  &lds[sl_ + 4096 + w * 512]); \
    gload16(gb_,                    &lds[sl_ + 8192 + w * 512]); \
    gload16(gb_ + (size_t)128 * K,  &lds[sl_ + 12288 + w * 512]); \
  }

  STAGE3(0) STAGE3(1) STAGE3(2)
  asm volatile("s_waitcnt vmcnt(8)" ::: "memory");
  __builtin_amdgcn_s_barrier();

  f32v4 acc[8][4] = {};
  const int nt = K >> 5;
  for (int t = 0; t < nt; ++t){
    if (t + 3 < nt) STAGE3(t + 3)
    const int sl = (t & 3) * 16384;
    bfv8 af[8], bfr[4];
    #pragma unroll
    for (int i = 0; i < 8; ++i)
      af[i] = ld8(&lds[sl + (wm * 128 + i * 16 + l15) * 32 + cbA]);
    #pragma unroll
    for (int j = 0; j < 4; ++j)
      bfr[j] = ld8(&lds[sl + 8192 + (wn * 64 + j * 16 + l15) * 32 + cbA]);
    __builtin_amdgcn_s_setprio(1);
    #pragma unroll
    for (int i = 0; i < 8; ++i)
      #pragma unroll
      for (int j = 0; j < 4; ++j)
        acc[i][j] = mfma16(af[i], bfr[j], acc[i][j]);
    __builtin_amdgcn_s_setprio(0);
    const int left = nt - 2 - t;
    if (left >= 2)      asm volatile("s_waitcnt vmcnt(8)" ::: "memory");
    else if (left == 1) asm volatile("s_waitcnt vmcnt(4)" ::: "memory");
    else                asm volatile("s_waitcnt vmcnt(0)" ::: "memory");
    __builtin_amdgcn_s_barrier();
  }
#undef STAGE3

  #pragma unroll
  for (int i = 0; i < 8; ++i){
    #pragma unroll
    for (int j = 0; j < 4; ++j){
      const int gr = bm + wm * 128 + i * 16 + lg * 4;
      const int gc = bn + wn * 64 + j * 16 + l15;
      #pragma unroll
      for (int r = 0; r < 4; ++r)
        Cp[(size_t)(gr + r) * N + gc] = f2bf(acc[i][j][r]);
    }
  }
}

// ---- C[M,N] = A[M,K] * B[N,K]^T, m97 structure (used for WO: N=2048) ----
template<bool CF32>
__global__ __launch_bounds__(256) void gemm2(const unsigned short* __restrict__ A,
                                             const unsigned short* __restrict__ B,
                                             void* __restrict__ Cp,
                                             int M, int N, int K){
  __shared__ unsigned short As[128 * 64];
  __shared__ unsigned short Bs[128 * 64];
  const int tid = threadIdx.x;
  const int lane = tid & 63;
  const int wave = tid >> 6;
  const int wr = (wave >> 1) * 64, wc = (wave & 1) * 64;
  const int bm = blockIdx.y * 128, bn = blockIdx.x * 128;
  const int l15 = lane & 15, lg = lane >> 4;
  const int lr = lane >> 3, lc = (lane & 7) * 8;

  f32v4 acc[4][4] = {};
  for (int kt = 0; kt < K; kt += 64){
    #pragma unroll
    for (int p = 0; p < 4; ++p){
      const int row = p * 32 + wave * 8 + lr;
      const int ldso = p * 2048 + wave * 512;
      gload16(&A[(size_t)(bm + row) * K + kt + lc], &As[ldso]);
      gload16(&B[(size_t)(bn + row) * K + kt + lc], &Bs[ldso]);
    }
    __syncthreads();
    #pragma unroll
    for (int kk = 0; kk < 64; kk += 32){
      bfv8 af[4], bfr[4];
      #pragma unroll
      for (int i = 0; i < 4; ++i) af[i] = ld8(&As[(wr + i * 16 + l15) * 64 + kk + lg * 8]);
      #pragma unroll
      for (int j = 0; j < 4; ++j) bfr[j] = ld8(&Bs[(wc + j * 16 + l15) * 64 + kk + lg * 8]);
      #pragma unroll
      for (int i = 0; i < 4; ++i)
        #pragma unroll
        for (int j = 0; j < 4; ++j)
          acc[i][j] = mfma16(af[i], bfr[j], acc[i][j]);
    }
    __syncthreads();
  }
  #pragma unroll
  for (int i = 0; i < 4; ++i){
    #pragma unroll
    for (int j = 0; j < 4; ++j){
      const int gr = bm + wr + i * 16 + lg * 4;
      const int gc = bn + wc + j * 16 + l15;
      #pragma unroll
      for (int r = 0; r < 4; ++r){
        if (CF32) reinterpret_cast<float*>(Cp)[(size_t)(gr + r) * N + gc] = acc[i][j][r];
        else reinterpret_cast<unsigned short*>(Cp)[(size_t)(gr + r) * N + gc] = f2bf(acc[i][j][r]);
      }
    }
  }
}

// ---- RoPE in-place on bf16 [rows][stride], rope'd cols 0..ncols-1, scaled ----
__global__ __launch_bounds__(256) void ropek(unsigned short* __restrict__ T,
                                             const float* __restrict__ fc,
                                             const float* __restrict__ fs, int ncols,
                                             int stride, float scale){
  int p = blockIdx.x * 256 + threadIdx.x;
  int half = ncols >> 1;
  int row = p / half;
  int pc = p - row * half;
  int h = pc >> 6, i = pc & 63;
  int s = row & (SEQL - 1);
  size_t idx = (size_t)row * stride + h * HD + 2 * i;
  float r = bf2f(T[idx]), im = bf2f(T[idx + 1]);
  float c = fc[s * 64 + i], sn = fs[s * 64 + i];
  T[idx]     = f2bf((r * c - im * sn) * scale);
  T[idx + 1] = f2bf((r * sn + im * c) * scale);
}

// ---- K swizzle + fused RoPE: QKVb fused [4096][4096] (K at col 2048) -> Kf ----
__global__ __launch_bounds__(256) void kswz(const unsigned short* __restrict__ QKVb,
                                            const float* __restrict__ fc,
                                            const float* __restrict__ fs,
                                            unsigned short* __restrict__ Kf){
  __shared__ unsigned short Ks[32][132];
  const int bk = blockIdx.y, kv32 = blockIdx.x;
  const int b = bk >> 3, kvh = bk & 7;
  const int t = threadIdx.x;
  const int r = t >> 3, cc = (t & 7) * 16;
  const int s = kv32 * 32 + r;
  const unsigned short* src = QKVb + (size_t)(b * SEQL + s) * 4096 + 2048 + kvh * HD + cc;
  s16v8 v0 = *reinterpret_cast<const s16v8*>(src);
  s16v8 v1 = *reinterpret_cast<const s16v8*>(src + 8);
  float4 c0 = *reinterpret_cast<const float4*>(&fc[s * 64 + (cc >> 1)]);
  float4 c1 = *reinterpret_cast<const float4*>(&fc[s * 64 + (cc >> 1) + 4]);
  float4 sv0 = *reinterpret_cast<const float4*>(&fs[s * 64 + (cc >> 1)]);
  float4 sv1 = *reinterpret_cast<const float4*>(&fs[s * 64 + (cc >> 1) + 4]);
  float cA[8] = {c0.x, c0.y, c0.z, c0.w, c1.x, c1.y, c1.z, c1.w};
  float sA[8] = {sv0.x, sv0.y, sv0.z, sv0.w, sv1.x, sv1.y, sv1.z, sv1.w};
  unsigned short e[16];
  #pragma unroll
  for (int k = 0; k < 8; ++k){ e[k] = (unsigned short)v0[k]; e[k + 8] = (unsigned short)v1[k]; }
  #pragma unroll
  for (int pi = 0; pi < 8; ++pi){
    float re = bf2f(e[2 * pi]), im = bf2f(e[2 * pi + 1]);
    Ks[r][cc + 2 * pi]     = f2bf(re * cA[pi] - im * sA[pi]);
    Ks[r][cc + 2 * pi + 1] = f2bf(re * sA[pi] + im * cA[pi]);
  }
  __syncthreads();
  const int l = t & 63;
  #pragma unroll
  for (int p = 0; p < 2; ++p){
    int ds = (t >> 6) * 2 + p;
    s16v8 val = *reinterpret_cast<const s16v8*>(&Ks[l & 31][ds * 16 + (l >> 5) * 8]);
    *reinterpret_cast<s16v8*>(&Kf[(((size_t)bk * 64 + kv32) * 8 + ds) * 512 + (size_t)l * 8]) = val;
  }
}

// ---- V swizzle: QKVb fused (V at col 3072) -> Vf fragment-major ----
__global__ __launch_bounds__(256) void vswz(const unsigned short* __restrict__ QKVb,
                                            unsigned short* __restrict__ Vf){
  __shared__ unsigned short Vs[32][132];
  const int bk = blockIdx.y, kv32 = blockIdx.x;
  const int b = bk >> 3, kvh = bk & 7;
  const int t = threadIdx.x;
  const int r = t >> 3, cc = (t & 7) * 16;
  const int s = kv32 * 32 + r;
  const unsigned short* src = QKVb + (size_t)(b * SEQL + s) * 4096 + 3072 + kvh * HD + cc;
  *reinterpret_cast<s16v8*>(&Vs[r][cc])     = *reinterpret_cast<const s16v8*>(src);
  *reinterpret_cast<s16v8*>(&Vs[r][cc + 8]) = *reinterpret_cast<const s16v8*>(src + 8);
  __syncthreads();
  const int dt = t >> 6, l = t & 63;
  #pragma unroll
  for (int h2 = 0; h2 < 2; ++h2){
    s16v8 val;
    #pragma unroll
    for (int j = 0; j < 8; ++j)
      val[j] = (short)Vs[h2 * 16 + (l >> 5) * 8 + j][dt * 32 + (l & 31)];
    *reinterpret_cast<s16v8*>(&Vf[(((size_t)bk * 64 + kv32) * 8 + dt * 2 + h2) * 512 + (size_t)l * 8]) = val;
  }
}

// ---- flash attention, causal, GQA(2): swapped 32x32, fragment-major K/V ----
__global__ __launch_bounds__(64) void fattn5(const unsigned short* __restrict__ Q,
                                             const unsigned short* __restrict__ Kf,
                                             const unsigned short* __restrict__ Vf,
                                             unsigned short* __restrict__ O){
  __shared__ __align__(16) unsigned short Ts[32][40];
  const int id = blockIdx.x;
  const int xcd = id & 7, sub = (id >> 3) & 3;
  const int bh = xcd * 4 + sub;
  const int qi = 63 - (id >> 5);            // heavy q-tiles dispatch first
  const int b = bh >> 4, h = bh & 15, kvh = h >> 1;
  const int bk = b * NKV + kvh;
  const int lane = threadIdx.x;
  const int c = lane & 31, hi = lane >> 5;
  const int q0 = qi * 32;
  const int q = q0 + c;

  bfv8 qf[8];
  {
    const unsigned short* qp = Q + (size_t)(b * SEQL + q) * 4096 + h * HD + hi * 8;
    #pragma unroll
    for (int ds = 0; ds < 8; ++ds) qf[ds] = ld8(qp + ds * 16);
  }

  f32v16 o0 = {}, o1 = {}, o2 = {}, o3 = {};
  float m = -1e30f, l = 0.f;

  const unsigned short* kfb = Kf + ((size_t)bk * 64) * 4096 + (size_t)lane * 8;
  const unsigned short* vfb = Vf + ((size_t)bk * 64) * 4096 + (size_t)lane * 8;

  bfv8 kf[8];
  #pragma unroll
  for (int ds = 0; ds < 8; ++ds) kf[ds] = ld8(kfb + ds * 512);

#define AITER(MASKED, PREF, IT) { \
    const unsigned short* vp = vfb + (size_t)(IT) * 4096; \
    bfv8 vf[8]; \
    _Pragma("unroll") \
    for (int dv = 0; dv < 8; ++dv) vf[dv] = ld8(vp + dv * 512); \
    f32v16 sa = {}, sb = {}; \
    __builtin_amdgcn_s_setprio(1); \
    _Pragma("unroll") \
    for (int ds = 0; ds < 4; ++ds){ \
      sa = mfma32(kf[ds], qf[ds], sa); \
      sb = mfma32(kf[ds + 4], qf[ds + 4], sb); \
    } \
    __builtin_amdgcn_s_setprio(0); \
    if (PREF){ \
      const unsigned short* kn = kfb + (size_t)((IT) + 1) * 4096; \
      _Pragma("unroll") \
      for (int ds = 0; ds < 8; ++ds) kf[ds] = ld8(kn + ds * 512); \
    } \
    float t[16]; \
    _Pragma("unroll") \
    for (int r = 0; r < 16; ++r){ \
      t[r] = sa[r] + sb[r]; \
      if (MASKED && ((r & 3) + 8 * (r >> 2) + 4 * hi) > c) t[r] = -3.0e38f; \
    } \
    float mx = t[0]; \
    _Pragma("unroll") \
    for (int r = 1; r < 16; ++r) mx = fmaxf(mx, t[r]); \
    mx = fmaxf(mx, __shfl_xor(mx, 32)); \
    if (!__all(mx - m <= 8.f)){ \
      float mn = fmaxf(m, mx); \
      float corr = __builtin_exp2f(m - mn); \
      l *= corr; \
      _Pragma("unroll") \
      for (int r = 0; r < 16; ++r){ o0[r]*=corr; o1[r]*=corr; o2[r]*=corr; o3[r]*=corr; } \
      m = mn; \
    } \
    float p[16], lsum = 0.f; \
    _Pragma("unroll") \
    for (int r = 0; r < 16; ++r){ p[r] = __builtin_exp2f(t[r] - m); lsum += p[r]; } \
    lsum += __shfl_xor(lsum, 32); \
    l += lsum; \
    unsigned w32[8]; \
    _Pragma("unroll") \
    for (int i = 0; i < 8; ++i){ \
      unsigned short lo_ = __builtin_bit_cast(unsigned short, (__bf16)p[2*i]); \
      unsigned short hb_ = __builtin_bit_cast(unsigned short, (__bf16)p[2*i+1]); \
      w32[i] = (unsigned)lo_ | ((unsigned)hb_ << 16); \
    } \
    i32v2 r0_ = __builtin_amdgcn_permlane32_swap((int)w32[0], (int)w32[2], false, false); \
    i32v2 r1_ = __builtin_amdgcn_permlane32_swap((int)w32[1], (int)w32[3], false, false); \
    i32v2 r2_ = __builtin_amdgcn_permlane32_swap((int)w32[4], (int)w32[6], false, false); \
    i32v2 r3_ = __builtin_amdgcn_permlane32_swap((int)w32[5], (int)w32[7], false, false); \
    u32v4 f0u, f1u; \
    f0u[0] = (unsigned)r0_[0]; f0u[1] = (unsigned)r1_[0]; \
    f0u[2] = (unsigned)r0_[1]; f0u[3] = (unsigned)r1_[1]; \
    f1u[0] = (unsigned)r2_[0]; f1u[1] = (unsigned)r3_[0]; \
    f1u[2] = (unsigned)r2_[1]; f1u[3] = (unsigned)r3_[1]; \
    bfv8 pf0 = __builtin_bit_cast(bfv8, f0u); \
    bfv8 pf1 = __builtin_bit_cast(bfv8, f1u); \
    __builtin_amdgcn_s_setprio(1); \
    o0 = mfma32(vf[0], pf0, o0); \
    o0 = mfma32(vf[1], pf1, o0); \
    o1 = mfma32(vf[2], pf0, o1); \
    o1 = mfma32(vf[3], pf1, o1); \
    o2 = mfma32(vf[4], pf0, o2); \
    o2 = mfma32(vf[5], pf1, o2); \
    o3 = mfma32(vf[6], pf0, o3); \
    o3 = mfma32(vf[7], pf1, o3); \
    __builtin_amdgcn_s_setprio(0); \
  }

  for (int it = 0; it < qi; ++it){
    AITER(false, true, it)
  }
  AITER(true, false, qi)
#undef AITER

  const float inv = 1.f / l;
  #define EPI(ODT, DT) \
  { \
    _Pragma("unroll") \
    for (int r = 0; r < 16; ++r) \
      Ts[c][(r & 3) + 8 * (r >> 2) + 4 * hi] = f2bf(ODT[r] * inv); \
    asm volatile("s_waitcnt lgkmcnt(0)" ::: "memory"); \
    _Pragma("unroll") \
    for (int pz = 0; pz < 2; ++pz){ \
      int qr = (lane >> 2) + pz * 16; \
      int dcol = (lane & 3) * 8; \
      s16v8 val = *reinterpret_cast<const s16v8*>(&Ts[qr][dcol]); \
      *reinterpret_cast<s16v8*>(&O[(size_t)(b * SEQL + q0 + qr) * DIMN + h * HD + DT * 32 + dcol]) = val; \
    } \
    asm volatile("s_waitcnt lgkmcnt(0)" ::: "memory"); \
  }
  EPI(o0, 0) EPI(o1, 1) EPI(o2, 2) EPI(o3, 3)
  #undef EPI
}

extern "C" void kernel_launch(void* const* d_in, const int* in_sizes, int n_in,
                              void* d_out, int out_size, void* d_ws, size_t ws_size,
                              hipStream_t stream){
  const float* x  = (const float*)d_in[0];
  const float* fc = (const float*)d_in[1];
  const float* fs = (const float*)d_in[2];
  const float* wq = (const float*)d_in[3];
  const float* wk = (const float*)d_in[4];
  const float* wv = (const float*)d_in[5];
  const float* wo = (const float*)d_in[6];
  float* out = (float*)d_out;
  char* ws = (char*)d_ws;
  unsigned short* xb   = (unsigned short*)(ws);              // 16 MB
  unsigned short* wqkv = (unsigned short*)(ws + 16777216);   // 16 MB fused [4096][2048] weights
  unsigned short* wkb  = (unsigned short*)(ws + 25165824);   //   (wk part, +4 MB)
  unsigned short* wvb  = (unsigned short*)(ws + 29360128);   //   (wv part, +4 MB)
  unsigned short* wob  = (unsigned short*)(ws + 33554432);   // 8 MB
  unsigned short* QKVb = (unsigned short*)(ws + 41943040);   // 32 MB fused [4096][4096]
  unsigned short* Ab   = (unsigned short*)(ws + 75497472);   // 16 MB
  unsigned short* Kf   = wqkv;                               // reuse weight slot (8 MB)
  unsigned short* Vf   = wkb;                                // reuse weight slot (8 MB)

  const float c1 = 0.08838834764831845f * 1.4426950408889634f;

  dim3 blk(256);
  cvtk<<<dim3(8192), blk, 0, stream>>>(x,  xb,  2097152);
  cvtk<<<dim3(4096), blk, 0, stream>>>(wq, wqkv, 1048576);
  cvtk<<<dim3(2048), blk, 0, stream>>>(wk, wkb,  524288);
  cvtk<<<dim3(2048), blk, 0, stream>>>(wv, wvb,  524288);
  cvtk<<<dim3(4096), blk, 0, stream>>>(wo, wob,  1048576);
  // fused QKV projection: [4096 tokens] x [4096 out] = Q | K | V  (deep-pipelined)
  gemm3<<<dim3(256), dim3(512), 0, stream>>>(xb, wqkv, QKVb, 4096, 4096, 2048);
  ropek<<<dim3(16384), blk, 0, stream>>>(QKVb, fc, fs, 2048, 4096, c1);
  kswz<<<dim3(64, 16), blk, 0, stream>>>(QKVb, fc, fs, Kf);
  vswz<<<dim3(64, 16), blk, 0, stream>>>(QKVb, Vf);
  fattn5<<<dim3(2048), dim3(64), 0, stream>>>(QKVb, Kf, Vf, Ab);
  gemm2<true><<<dim3(16, 32), blk, 0, stream>>>(Ab, wob, out, 4096, 2048, 2048);
}

// Round 7
// 209.371 us; speedup vs baseline: 3.5443x; 1.0782x over previous
//
#include <hip/hip_runtime.h>
#include <hip/hip_bf16.h>

#define SEQL 2048
#define DIMN 2048
#define NH 16
#define NKV 8
#define HD 128
#define NB 2

typedef float f32v4 __attribute__((ext_vector_type(4)));
typedef float f32v16 __attribute__((ext_vector_type(16)));
typedef __bf16 bfv8 __attribute__((ext_vector_type(8)));
typedef short s16v8 __attribute__((ext_vector_type(8)));
typedef unsigned short u16v4 __attribute__((ext_vector_type(4)));
typedef unsigned int u32v4 __attribute__((ext_vector_type(4)));
typedef int i32v2 __attribute__((ext_vector_type(2)));

__device__ inline unsigned short f2bf(float f){
  union { float f; unsigned u; } v; v.f = f;
  unsigned r = (v.u + 0x7fffu + ((v.u >> 16) & 1u)) >> 16;
  return (unsigned short)r;
}
__device__ inline float bf2f(unsigned short u){
  union { unsigned u; float f; } v; v.u = ((unsigned)u) << 16;
  return v.f;
}
__device__ inline f32v4 mfma16(bfv8 a, bfv8 b, f32v4 c){
  return __builtin_amdgcn_mfma_f32_16x16x32_bf16(a, b, c, 0, 0, 0);
}
__device__ inline f32v16 mfma32(bfv8 a, bfv8 b, f32v16 c){
  return __builtin_amdgcn_mfma_f32_32x32x16_bf16(a, b, c, 0, 0, 0);
}
__device__ inline bfv8 ld8(const unsigned short* p){
  s16v8 v = *reinterpret_cast<const s16v8*>(p);
  return __builtin_bit_cast(bfv8, v);
}
__device__ inline void gload16(const void* g, void* l){
  __builtin_amdgcn_global_load_lds(
      (const __attribute__((address_space(1))) unsigned int*)g,
      (__attribute__((address_space(3))) unsigned int*)l, 16, 0, 0);
}

// ---- fused fp32 -> bf16 convert for all 5 inputs (one dispatch) ----
__global__ __launch_bounds__(256) void cvtall(const float* __restrict__ x,
                                              const float* __restrict__ wq,
                                              const float* __restrict__ wk,
                                              const float* __restrict__ wv,
                                              const float* __restrict__ wo,
                                              unsigned short* __restrict__ xb,
                                              unsigned short* __restrict__ wqkvb,
                                              unsigned short* __restrict__ wob){
  const int bid = blockIdx.x;
  const float* src; unsigned short* dst; int off;
  if (bid < 8192)       { src = x;  dst = xb;              off = bid; }
  else if (bid < 12288) { src = wq; dst = wqkvb;           off = bid - 8192; }
  else if (bid < 14336) { src = wk; dst = wqkvb + 4194304; off = bid - 12288; }
  else if (bid < 16384) { src = wv; dst = wqkvb + 6291456; off = bid - 14336; }
  else                  { src = wo; dst = wob;             off = bid - 16384; }
  const int i = off * 256 + threadIdx.x;
  const float4 v = reinterpret_cast<const float4*>(src)[i];
  u16v4 w; w[0] = f2bf(v.x); w[1] = f2bf(v.y); w[2] = f2bf(v.z); w[3] = f2bf(v.w);
  reinterpret_cast<u16v4*>(dst)[i] = w;
}

// ---- deep-pipelined 256x256 GEMM: C = A * B^T, bf16 out ----
// BK=32, 4-slot LDS ring, counted vmcnt, XOR swizzle, 2-phase interleave:
// P1{read bf+af[0-3], stage A, barrier, 16 MFMA} P2{read af[4-7], stage B, 16 MFMA}.
__global__ __launch_bounds__(512, 2) void gemm3(const unsigned short* __restrict__ A,
                                                const unsigned short* __restrict__ B,
                                                unsigned short* __restrict__ Cp,
                                                int M, int N, int K){
  __shared__ unsigned short lds[65536];   // 4 slots x 16384 elems = 128 KB
  const int tid = threadIdx.x;
  const int lane = tid & 63, w = tid >> 6;
  const int wm = w >> 2, wn = w & 3;
  const int nbx = N >> 8;
  const int nwg = gridDim.x;
  const int cpx = nwg >> 3;
  const int id = blockIdx.x;
  const int swz = (id & 7) * cpx + (id >> 3);   // XCD-affine (nwg % 8 == 0)
  const int bm = (swz / nbx) * 256, bn = (swz % nbx) * 256;
  const int l15 = lane & 15, lg = lane >> 4;
  const int srow = w * 16 + (lane >> 2);
  const int cbg = ((lane & 3) ^ ((lane >> 3) & 3)) * 8;
  const int cbA = (lg ^ ((l15 >> 1) & 3)) * 8;

#define STAGE_A(T) { \
    const int kt_ = (T) * 32; \
    const int sl_ = ((T) & 3) * 16384; \
    const unsigned short* ga_ = &A[(size_t)(bm + srow) * K + kt_ + cbg]; \
    gload16(ga_,                    &lds[sl_ + w * 512]); \
    gload16(ga_ + (size_t)128 * K,  &lds[sl_ + 4096 + w * 512]); \
  }
#define STAGE_B(T) { \
    const int kt_ = (T) * 32; \
    const int sl_ = ((T) & 3) * 16384; \
    const unsigned short* gb_ = &B[(size_t)(bn + srow) * K + kt_ + cbg]; \
    gload16(gb_,                    &lds[sl_ + 8192 + w * 512]); \
    gload16(gb_ + (size_t)128 * K,  &lds[sl_ + 12288 + w * 512]); \
  }

  STAGE_A(0) STAGE_B(0) STAGE_A(1) STAGE_B(1) STAGE_A(2) STAGE_B(2)
  asm volatile("s_waitcnt vmcnt(8)" ::: "memory");
  __builtin_amdgcn_s_barrier();

  f32v4 acc[8][4] = {};
  const int nt = K >> 5;
  for (int t = 0; t < nt; ++t){
    const bool st = (t + 3 < nt);
    const int sl = (t & 3) * 16384;
    bfv8 af[8], bfr[4];
    // phase 1: reads for lower quadrant + A-stage, barrier, MFMA
    #pragma unroll
    for (int j = 0; j < 4; ++j)
      bfr[j] = ld8(&lds[sl + 8192 + (wn * 64 + j * 16 + l15) * 32 + cbA]);
    #pragma unroll
    for (int i = 0; i < 4; ++i)
      af[i] = ld8(&lds[sl + (wm * 128 + i * 16 + l15) * 32 + cbA]);
    if (st) STAGE_A(t + 3)
    __builtin_amdgcn_s_barrier();
    __builtin_amdgcn_s_setprio(1);
    #pragma unroll
    for (int i = 0; i < 4; ++i)
      #pragma unroll
      for (int j = 0; j < 4; ++j)
        acc[i][j] = mfma16(af[i], bfr[j], acc[i][j]);
    __builtin_amdgcn_s_setprio(0);
    // phase 2: reads for upper quadrant + B-stage, MFMA
    #pragma unroll
    for (int i = 4; i < 8; ++i)
      af[i] = ld8(&lds[sl + (wm * 128 + i * 16 + l15) * 32 + cbA]);
    if (st) STAGE_B(t + 3)
    __builtin_amdgcn_s_setprio(1);
    #pragma unroll
    for (int i = 4; i < 8; ++i)
      #pragma unroll
      for (int j = 0; j < 4; ++j)
        acc[i][j] = mfma16(af[i], bfr[j], acc[i][j]);
    __builtin_amdgcn_s_setprio(0);
    if (st)                asm volatile("s_waitcnt vmcnt(8)" ::: "memory");
    else if (t == nt - 3)  asm volatile("s_waitcnt vmcnt(4)" ::: "memory");
    else                   asm volatile("s_waitcnt vmcnt(0)" ::: "memory");
    __builtin_amdgcn_s_barrier();
  }
#undef STAGE_A
#undef STAGE_B

  #pragma unroll
  for (int i = 0; i < 8; ++i){
    #pragma unroll
    for (int j = 0; j < 4; ++j){
      const int gr = bm + wm * 128 + i * 16 + lg * 4;
      const int gc = bn + wn * 64 + j * 16 + l15;
      #pragma unroll
      for (int r = 0; r < 4; ++r)
        Cp[(size_t)(gr + r) * N + gc] = f2bf(acc[i][j][r]);
    }
  }
}

// ---- deep-pipelined 256x128 GEMM: C = A * B^T, fp32 out (WO projection) ----
// Same ring protocol, 3 gloads/stage -> vmcnt(6)/(3)/(0). 8 waves 4x2, 64x64/wave.
__global__ __launch_bounds__(512, 2) void gemm3n(const unsigned short* __restrict__ A,
                                                 const unsigned short* __restrict__ B,
                                                 float* __restrict__ Cp,
                                                 int M, int N, int K){
  __shared__ unsigned short lds[49152];   // 4 slots x 12288 elems = 96 KB
  const int tid = threadIdx.x;
  const int lane = tid & 63, w = tid >> 6;
  const int wm = w >> 1, wn = w & 1;
  const int nbx = N >> 7;
  const int nwg = gridDim.x;
  const int cpx = nwg >> 3;
  const int id = blockIdx.x;
  const int swz = (id & 7) * cpx + (id >> 3);
  const int bm = (swz / nbx) * 256, bn = (swz % nbx) * 128;
  const int l15 = lane & 15, lg = lane >> 4;
  const int srow = tid >> 2;                       // 0..127
  const int cbg = ((tid & 3) ^ ((tid >> 3) & 3)) * 8;
  const int cbA = (lg ^ ((l15 >> 1) & 3)) * 8;

#define STAGEN(T) { \
    const int kt_ = (T) * 32; \
    const int sl_ = ((T) & 3) * 12288; \
    const unsigned short* ga_ = &A[(size_t)(bm + srow) * K + kt_ + cbg]; \
    gload16(ga_,                    &lds[sl_ + w * 512]); \
    gload16(ga_ + (size_t)128 * K,  &lds[sl_ + 4096 + w * 512]); \
    const unsigned short* gb_ = &B[(size_t)(bn + srow) * K + kt_ + cbg]; \
    gload16(gb_,                    &lds[sl_ + 8192 + w * 512]); \
  }

  STAGEN(0) STAGEN(1) STAGEN(2)
  asm volatile("s_waitcnt vmcnt(6)" ::: "memory");
  __builtin_amdgcn_s_barrier();

  f32v4 acc[4][4] = {};
  const int nt = K >> 5;
  for (int t = 0; t < nt; ++t){
    const bool st = (t + 3 < nt);
    if (st) STAGEN(t + 3)
    const int sl = (t & 3) * 12288;
    bfv8 af[4], bfr[4];
    #pragma unroll
    for (int i = 0; i < 4; ++i)
      af[i] = ld8(&lds[sl + (wm * 64 + i * 16 + l15) * 32 + cbA]);
    #pragma unroll
    for (int j = 0; j < 4; ++j)
      bfr[j] = ld8(&lds[sl + 8192 + (wn * 64 + j * 16 + l15) * 32 + cbA]);
    __builtin_amdgcn_s_setprio(1);
    #pragma unroll
    for (int i = 0; i < 4; ++i)
      #pragma unroll
      for (int j = 0; j < 4; ++j)
        acc[i][j] = mfma16(af[i], bfr[j], acc[i][j]);
    __builtin_amdgcn_s_setprio(0);
    if (st)                asm volatile("s_waitcnt vmcnt(6)" ::: "memory");
    else if (t == nt - 3)  asm volatile("s_waitcnt vmcnt(3)" ::: "memory");
    else                   asm volatile("s_waitcnt vmcnt(0)" ::: "memory");
    __builtin_amdgcn_s_barrier();
  }
#undef STAGEN

  #pragma unroll
  for (int i = 0; i < 4; ++i){
    #pragma unroll
    for (int j = 0; j < 4; ++j){
      const int gr = bm + wm * 64 + i * 16 + lg * 4;
      const int gc = bn + wn * 64 + j * 16 + l15;
      #pragma unroll
      for (int r = 0; r < 4; ++r)
        Cp[(size_t)(gr + r) * N + gc] = acc[i][j][r];
    }
  }
}

// ---- RoPE in-place on bf16 [rows][stride], rope'd cols 0..ncols-1, scaled ----
__global__ __launch_bounds__(256) void ropek(unsigned short* __restrict__ T,
                                             const float* __restrict__ fc,
                                             const float* __restrict__ fs, int ncols,
                                             int stride, float scale){
  int p = blockIdx.x * 256 + threadIdx.x;
  int half = ncols >> 1;
  int row = p / half;
  int pc = p - row * half;
  int h = pc >> 6, i = pc & 63;
  int s = row & (SEQL - 1);
  size_t idx = (size_t)row * stride + h * HD + 2 * i;
  float r = bf2f(T[idx]), im = bf2f(T[idx + 1]);
  float c = fc[s * 64 + i], sn = fs[s * 64 + i];
  T[idx]     = f2bf((r * c - im * sn) * scale);
  T[idx + 1] = f2bf((r * sn + im * c) * scale);
}

// ---- K swizzle + fused RoPE: QKVb fused [4096][4096] (K at col 2048) -> Kf ----
__global__ __launch_bounds__(256) void kswz(const unsigned short* __restrict__ QKVb,
                                            const float* __restrict__ fc,
                                            const float* __restrict__ fs,
                                            unsigned short* __restrict__ Kf){
  __shared__ unsigned short Ks[32][132];
  const int bk = blockIdx.y, kv32 = blockIdx.x;
  const int b = bk >> 3, kvh = bk & 7;
  const int t = threadIdx.x;
  const int r = t >> 3, cc = (t & 7) * 16;
  const int s = kv32 * 32 + r;
  const unsigned short* src = QKVb + (size_t)(b * SEQL + s) * 4096 + 2048 + kvh * HD + cc;
  s16v8 v0 = *reinterpret_cast<const s16v8*>(src);
  s16v8 v1 = *reinterpret_cast<const s16v8*>(src + 8);
  float4 c0 = *reinterpret_cast<const float4*>(&fc[s * 64 + (cc >> 1)]);
  float4 c1 = *reinterpret_cast<const float4*>(&fc[s * 64 + (cc >> 1) + 4]);
  float4 sv0 = *reinterpret_cast<const float4*>(&fs[s * 64 + (cc >> 1)]);
  float4 sv1 = *reinterpret_cast<const float4*>(&fs[s * 64 + (cc >> 1) + 4]);
  float cA[8] = {c0.x, c0.y, c0.z, c0.w, c1.x, c1.y, c1.z, c1.w};
  float sA[8] = {sv0.x, sv0.y, sv0.z, sv0.w, sv1.x, sv1.y, sv1.z, sv1.w};
  unsigned short e[16];
  #pragma unroll
  for (int k = 0; k < 8; ++k){ e[k] = (unsigned short)v0[k]; e[k + 8] = (unsigned short)v1[k]; }
  #pragma unroll
  for (int pi = 0; pi < 8; ++pi){
    float re = bf2f(e[2 * pi]), im = bf2f(e[2 * pi + 1]);
    Ks[r][cc + 2 * pi]     = f2bf(re * cA[pi] - im * sA[pi]);
    Ks[r][cc + 2 * pi + 1] = f2bf(re * sA[pi] + im * cA[pi]);
  }
  __syncthreads();
  const int l = t & 63;
  #pragma unroll
  for (int p = 0; p < 2; ++p){
    int ds = (t >> 6) * 2 + p;
    s16v8 val = *reinterpret_cast<const s16v8*>(&Ks[l & 31][ds * 16 + (l >> 5) * 8]);
    *reinterpret_cast<s16v8*>(&Kf[(((size_t)bk * 64 + kv32) * 8 + ds) * 512 + (size_t)l * 8]) = val;
  }
}

// ---- V swizzle: QKVb fused (V at col 3072) -> Vf fragment-major ----
__global__ __launch_bounds__(256) void vswz(const unsigned short* __restrict__ QKVb,
                                            unsigned short* __restrict__ Vf){
  __shared__ unsigned short Vs[32][132];
  const int bk = blockIdx.y, kv32 = blockIdx.x;
  const int b = bk >> 3, kvh = bk & 7;
  const int t = threadIdx.x;
  const int r = t >> 3, cc = (t & 7) * 16;
  const int s = kv32 * 32 + r;
  const unsigned short* src = QKVb + (size_t)(b * SEQL + s) * 4096 + 3072 + kvh * HD + cc;
  *reinterpret_cast<s16v8*>(&Vs[r][cc])     = *reinterpret_cast<const s16v8*>(src);
  *reinterpret_cast<s16v8*>(&Vs[r][cc + 8]) = *reinterpret_cast<const s16v8*>(src + 8);
  __syncthreads();
  const int dt = t >> 6, l = t & 63;
  #pragma unroll
  for (int h2 = 0; h2 < 2; ++h2){
    s16v8 val;
    #pragma unroll
    for (int j = 0; j < 8; ++j)
      val[j] = (short)Vs[h2 * 16 + (l >> 5) * 8 + j][dt * 32 + (l & 31)];
    *reinterpret_cast<s16v8*>(&Vf[(((size_t)bk * 64 + kv32) * 8 + dt * 2 + h2) * 512 + (size_t)l * 8]) = val;
  }
}

// ---- flash attention, causal, GQA(2): swapped 32x32, fragment-major K/V ----
__global__ __launch_bounds__(64) void fattn5(const unsigned short* __restrict__ Q,
                                             const unsigned short* __restrict__ Kf,
                                             const unsigned short* __restrict__ Vf,
                                             unsigned short* __restrict__ O){
  __shared__ __align__(16) unsigned short Ts[32][40];
  const int id = blockIdx.x;
  const int xcd = id & 7, sub = (id >> 3) & 3;
  const int bh = xcd * 4 + sub;
  const int qi = 63 - (id >> 5);            // heavy q-tiles dispatch first
  const int b = bh >> 4, h = bh & 15, kvh = h >> 1;
  const int bk = b * NKV + kvh;
  const int lane = threadIdx.x;
  const int c = lane & 31, hi = lane >> 5;
  const int q0 = qi * 32;
  const int q = q0 + c;

  bfv8 qf[8];
  {
    const unsigned short* qp = Q + (size_t)(b * SEQL + q) * 4096 + h * HD + hi * 8;
    #pragma unroll
    for (int ds = 0; ds < 8; ++ds) qf[ds] = ld8(qp + ds * 16);
  }

  f32v16 o0 = {}, o1 = {}, o2 = {}, o3 = {};
  float m = -1e30f, l = 0.f;

  const unsigned short* kfb = Kf + ((size_t)bk * 64) * 4096 + (size_t)lane * 8;
  const unsigned short* vfb = Vf + ((size_t)bk * 64) * 4096 + (size_t)lane * 8;

  bfv8 kf[8];
  #pragma unroll
  for (int ds = 0; ds < 8; ++ds) kf[ds] = ld8(kfb + ds * 512);

#define AITER(MASKED, PREF, IT) { \
    const unsigned short* vp = vfb + (size_t)(IT) * 4096; \
    bfv8 vf[8]; \
    _Pragma("unroll") \
    for (int dv = 0; dv < 8; ++dv) vf[dv] = ld8(vp + dv * 512); \
    f32v16 sa = {}, sb = {}; \
    __builtin_amdgcn_s_setprio(1); \
    _Pragma("unroll") \
    for (int ds = 0; ds < 4; ++ds){ \
      sa = mfma32(kf[ds], qf[ds], sa); \
      sb = mfma32(kf[ds + 4], qf[ds + 4], sb); \
    } \
    __builtin_amdgcn_s_setprio(0); \
    if (PREF){ \
      const unsigned short* kn = kfb + (size_t)((IT) + 1) * 4096; \
      _Pragma("unroll") \
      for (int ds = 0; ds < 8; ++ds) kf[ds] = ld8(kn + ds * 512); \
    } \
    float t[16]; \
    _Pragma("unroll") \
    for (int r = 0; r < 16; ++r){ \
      t[r] = sa[r] + sb[r]; \
      if (MASKED && ((r & 3) + 8 * (r >> 2) + 4 * hi) > c) t[r] = -3.0e38f; \
    } \
    float mx = t[0]; \
    _Pragma("unroll") \
    for (int r = 1; r < 16; ++r) mx = fmaxf(mx, t[r]); \
    mx = fmaxf(mx, __shfl_xor(mx, 32)); \
    if (!__all(mx - m <= 8.f)){ \
      float mn = fmaxf(m, mx); \
      float corr = __builtin_exp2f(m - mn); \
      l *= corr; \
      _Pragma("unroll") \
      for (int r = 0; r < 16; ++r){ o0[r]*=corr; o1[r]*=corr; o2[r]*=corr; o3[r]*=corr; } \
      m = mn; \
    } \
    float p[16], lsum = 0.f; \
    _Pragma("unroll") \
    for (int r = 0; r < 16; ++r){ p[r] = __builtin_exp2f(t[r] - m); lsum += p[r]; } \
    lsum += __shfl_xor(lsum, 32); \
    l += lsum; \
    unsigned w32[8]; \
    _Pragma("unroll") \
    for (int i = 0; i < 8; ++i){ \
      unsigned short lo_ = __builtin_bit_cast(unsigned short, (__bf16)p[2*i]); \
      unsigned short hb_ = __builtin_bit_cast(unsigned short, (__bf16)p[2*i+1]); \
      w32[i] = (unsigned)lo_ | ((unsigned)hb_ << 16); \
    } \
    i32v2 r0_ = __builtin_amdgcn_permlane32_swap((int)w32[0], (int)w32[2], false, false); \
    i32v2 r1_ = __builtin_amdgcn_permlane32_swap((int)w32[1], (int)w32[3], false, false); \
    i32v2 r2_ = __builtin_amdgcn_permlane32_swap((int)w32[4], (int)w32[6], false, false); \
    i32v2 r3_ = __builtin_amdgcn_permlane32_swap((int)w32[5], (int)w32[7], false, false); \
    u32v4 f0u, f1u; \
    f0u[0] = (unsigned)r0_[0]; f0u[1] = (unsigned)r1_[0]; \
    f0u[2] = (unsigned)r0_[1]; f0u[3] = (unsigned)r1_[1]; \
    f1u[0] = (unsigned)r2_[0]; f1u[1] = (unsigned)r3_[0]; \
    f1u[2] = (unsigned)r2_[1]; f1u[3] = (unsigned)r3_[1]; \
    bfv8 pf0 = __builtin_bit_cast(bfv8, f0u); \
    bfv8 pf1 = __builtin_bit_cast(bfv8, f1u); \
    __builtin_amdgcn_s_setprio(1); \
    o0 = mfma32(vf[0], pf0, o0); \
    o0 = mfma32(vf[1], pf1, o0); \
    o1 = mfma32(vf[2], pf0, o1); \
    o1 = mfma32(vf[3], pf1, o1); \
    o2 = mfma32(vf[4], pf0, o2); \
    o2 = mfma32(vf[5], pf1, o2); \
    o3 = mfma32(vf[6], pf0, o3); \
    o3 = mfma32(vf[7], pf1, o3); \
    __builtin_amdgcn_s_setprio(0); \
  }

  for (int it = 0; it < qi; ++it){
    AITER(false, true, it)
  }
  AITER(true, false, qi)
#undef AITER

  const float inv = 1.f / l;
  #define EPI(ODT, DT) \
  { \
    _Pragma("unroll") \
    for (int r = 0; r < 16; ++r) \
      Ts[c][(r & 3) + 8 * (r >> 2) + 4 * hi] = f2bf(ODT[r] * inv); \
    asm volatile("s_waitcnt lgkmcnt(0)" ::: "memory"); \
    _Pragma("unroll") \
    for (int pz = 0; pz < 2; ++pz){ \
      int qr = (lane >> 2) + pz * 16; \
      int dcol = (lane & 3) * 8; \
      s16v8 val = *reinterpret_cast<const s16v8*>(&Ts[qr][dcol]); \
      *reinterpret_cast<s16v8*>(&O[(size_t)(b * SEQL + q0 + qr) * DIMN + h * HD + DT * 32 + dcol]) = val; \
    } \
    asm volatile("s_waitcnt lgkmcnt(0)" ::: "memory"); \
  }
  EPI(o0, 0) EPI(o1, 1) EPI(o2, 2) EPI(o3, 3)
  #undef EPI
}

extern "C" void kernel_launch(void* const* d_in, const int* in_sizes, int n_in,
                              void* d_out, int out_size, void* d_ws, size_t ws_size,
                              hipStream_t stream){
  const float* x  = (const float*)d_in[0];
  const float* fc = (const float*)d_in[1];
  const float* fs = (const float*)d_in[2];
  const float* wq = (const float*)d_in[3];
  const float* wk = (const float*)d_in[4];
  const float* wv = (const float*)d_in[5];
  const float* wo = (const float*)d_in[6];
  float* out = (float*)d_out;
  char* ws = (char*)d_ws;
  unsigned short* xb   = (unsigned short*)(ws);              // 16 MB
  unsigned short* wqkv = (unsigned short*)(ws + 16777216);   // 16 MB fused [4096][2048] weights
  unsigned short* wkb  = (unsigned short*)(ws + 25165824);   //   (wk part)
  unsigned short* wob  = (unsigned short*)(ws + 33554432);   // 8 MB
  unsigned short* QKVb = (unsigned short*)(ws + 41943040);   // 32 MB fused [4096][4096]
  unsigned short* Ab   = (unsigned short*)(ws + 75497472);   // 16 MB
  unsigned short* Kf   = wqkv;                               // reuse weight slot (8 MB)
  unsigned short* Vf   = wkb;                                // reuse weight slot (8 MB)

  const float c1 = 0.08838834764831845f * 1.4426950408889634f;

  dim3 blk(256);
  cvtall<<<dim3(20480), blk, 0, stream>>>(x, wq, wk, wv, wo, xb, wqkv, wob);
  // fused QKV projection: [4096 tokens] x [4096 out] = Q | K | V  (2-phase pipelined)
  gemm3<<<dim3(256), dim3(512), 0, stream>>>(xb, wqkv, QKVb, 4096, 4096, 2048);
  ropek<<<dim3(16384), blk, 0, stream>>>(QKVb, fc, fs, 2048, 4096, c1);
  kswz<<<dim3(64, 16), blk, 0, stream>>>(QKVb, fc, fs, Kf);
  vswz<<<dim3(64, 16), blk, 0, stream>>>(QKVb, Vf);
  fattn5<<<dim3(2048), dim3(64), 0, stream>>>(QKVb, Kf, Vf, Ab);
  gemm3n<<<dim3(256), dim3(512), 0, stream>>>(Ab, wob, out, 4096, 2048, 2048);
}